// Round 6
// baseline (327.850 us; speedup 1.0000x reference)
//
#include <hip/hip_runtime.h>
#include <hip/hip_bf16.h>

// GCN: h1 = relu(GCNConv(x, W1, b1)); out = scatter_mean(GCNConv(h1, W2, b2), user_idx)
// N=100000, E=1600000, dims 128 -> 64 -> 64. fp32 I/O, int32 indices.
//
// R16/R17: agg gather is at the random-128B-line HBM roofline (FETCH 86MB =
// cross-XCD duplication of the 12.8MB A array; ~2.6TB/s scattered). 42us/agg
// is structural. R17 (gemm2 fused into agg1) verified: 276->259.
// R18: cut dispatches 8->6 + overlap gemm1:
//  (1) bscan fused into bhist (last-block-done pattern, atomic gbc reads);
//  (2) gemm1 fused into binB2 (k_binB2g): bucket block already has per-node
//      degrees in LDS -> dis locally; 16 waves x 32 rows x MFMA after the
//      scatter phase. A gets own buffer; A2 reuses the dead pairs region.

#define FEAT 64
#define INDIM 128

#define SCAN_BS 256
#define SCAN_ELEMS 8
#define SCAN_CHUNK (SCAN_BS * SCAN_ELEMS)

#define BIN_SHIFT 9
#define BIN_R 512
#define BIN_TILE 2048
#define BH_TILE 2048

typedef __attribute__((ext_vector_type(8))) short short8;
typedef __attribute__((ext_vector_type(4))) float f32x4;

__device__ __forceinline__ unsigned short f2bf(float f) {
    unsigned u = __float_as_uint(f);
    unsigned r = u + 0x7FFFu + ((u >> 16) & 1u);
    return (unsigned short)(r >> 16);
}
__device__ __forceinline__ float bf2f(unsigned short v) {
    return __uint_as_float(((unsigned)v) << 16);
}

// ==================== bucket-level CSR build ====================

// histogram + ucnt + optional out-zeroing + LAST-BLOCK bucket scan
__global__ __launch_bounds__(256) void k_bhist2(const int* __restrict__ dst,
                                                int* __restrict__ gbc,
                                                const int* __restrict__ uidx,
                                                float* __restrict__ cntf,
                                                uint4* __restrict__ outz, long nz4,
                                                unsigned* __restrict__ done,
                                                int* __restrict__ bb,
                                                int* __restrict__ bcur,
                                                int* __restrict__ rpN,
                                                int E, int N, int KB) {
    __shared__ int h[256];
    __shared__ int isLast;
    const int tid = threadIdx.x;
    h[tid] = 0;
    __syncthreads();
    const int base = blockIdx.x * BH_TILE;
    #pragma unroll
    for (int t = 0; t < BH_TILE / 256; ++t) {
        int e = base + t * 256 + tid;
        if (e < E) {
            int d = dst[e];
            if ((unsigned)d < (unsigned)N) atomicAdd(&h[d >> BIN_SHIFT], 1);
        }
    }
    int i = blockIdx.x * 256 + tid;
    if (i < N) {
        int u = uidx[i];
        if ((unsigned)u < (unsigned)N) atomicAdd(&cntf[u], 1.0f);
    }
    if (outz) {
        uint4 z; z.x = 0; z.y = 0; z.z = 0; z.w = 0;
        const long stride = (long)gridDim.x * 256;
        for (long idx = (long)blockIdx.x * 256 + tid; idx < nz4; idx += stride)
            outz[idx] = z;
    }
    __syncthreads();
    if (tid < KB && h[tid]) atomicAdd(&gbc[tid], h[tid]);
    __threadfence();                      // publish this thread's atomics
    __syncthreads();
    if (tid == 0) {
        unsigned t = atomicAdd(done, 1u);
        isLast = (t == (unsigned)(gridDim.x - 1));
    }
    __syncthreads();
    if (isLast) {
        __threadfence();                  // acquire
        int v = (tid < KB) ? atomicAdd(&gbc[tid], 0) : 0;   // coherent read
        h[tid] = v;
        __syncthreads();
        for (int d = 1; d < 256; d <<= 1) {
            int t2 = (tid >= d) ? h[tid - d] : 0;
            __syncthreads();
            h[tid] += t2;
            __syncthreads();
        }
        int excl = h[tid] - v;
        if (tid < KB) { bb[tid] = excl; bcur[tid] = excl; }
        if (tid == 255) { bb[KB] = h[255]; *rpN = h[255]; }
    }
}

// tile-reorder edges by bucket; packed (src<<BIN_SHIFT)|local_dst
__global__ __launch_bounds__(256) void k_binA(const int* __restrict__ src,
                                              const int* __restrict__ dst,
                                              int* __restrict__ bcur,
                                              unsigned* __restrict__ pairs,
                                              int E, int N, int KB) {
    __shared__ unsigned lbuf[BIN_TILE];          // 8 KB
    __shared__ unsigned short bkt[BIN_TILE];     // 4 KB
    __shared__ int lcnt[256];
    __shared__ int loff[256];
    __shared__ int lbase[256];
    __shared__ int tot;
    const int tid = threadIdx.x;
    const int base = blockIdx.x * BIN_TILE;

    lcnt[tid] = 0;
    __syncthreads();

    int mys[BIN_TILE / 256], myd[BIN_TILE / 256], myb[BIN_TILE / 256];
    #pragma unroll
    for (int t = 0; t < BIN_TILE / 256; ++t) {
        int e = base + t * 256 + tid;
        int s = 0, d = -1;
        if (e < E) { s = src[e]; d = dst[e]; }
        if ((unsigned)d >= (unsigned)N) d = -1;
        if ((unsigned)s >= (unsigned)N) s = 0;
        mys[t] = s; myd[t] = d;
        myb[t] = (d >= 0) ? (d >> BIN_SHIFT) : -1;
        if (myb[t] >= 0) atomicAdd(&lcnt[myb[t]], 1);
    }
    __syncthreads();

    int v = lcnt[tid];
    loff[tid] = v;
    __syncthreads();
    for (int d = 1; d < 256; d <<= 1) {
        int t2 = (tid >= d) ? loff[tid - d] : 0;
        __syncthreads();
        loff[tid] += t2;
        __syncthreads();
    }
    if (tid == 255) tot = loff[255];
    int excl = loff[tid] - v;
    __syncthreads();
    loff[tid] = excl;
    lcnt[tid] = excl;
    if (tid < KB && v > 0) lbase[tid] = atomicAdd(&bcur[tid], v);
    __syncthreads();

    #pragma unroll
    for (int t = 0; t < BIN_TILE / 256; ++t) {
        if (myb[t] >= 0) {
            int pos = atomicAdd(&lcnt[myb[t]], 1);
            lbuf[pos] = ((unsigned)mys[t] << BIN_SHIFT) | (unsigned)(myd[t] & (BIN_R - 1));
            bkt[pos] = (unsigned short)myb[t];
        }
    }
    __syncthreads();

    const int T = tot;
    for (int i = tid; i < T; i += 256) {
        int b = bkt[i];
        pairs[lbase[b] + (i - loff[b])] = lbuf[i];
    }
}

// FUSED binB2+gemm1: one WG (16 waves) per bucket of 512 nodes.
// Phase A: degrees in LDS -> rp + dis, rank -> col (as binB2).
// Phase B: each wave MFMAs two 16-row tiles of A = rsqrt(cnt+1)*(x@W1)
// using the LDS degree counts directly (identical value to dis[row]).
__global__ __launch_bounds__(1024) void k_binB2g(const unsigned* __restrict__ pairs,
                                                 const int* __restrict__ bb,
                                                 int* __restrict__ rp,
                                                 int* __restrict__ col,
                                                 float* __restrict__ dis,
                                                 const float* __restrict__ x,
                                                 const float* __restrict__ W1,
                                                 unsigned short* __restrict__ A, int N) {
    __shared__ int cnt[BIN_R];
    __shared__ int cur[BIN_R];
    __shared__ int ssum[256];
    __shared__ short wf[4 * 4 * 64 * 8];   // W1 fragments, 16 KB
    const int tid = threadIdx.x;
    const int b = blockIdx.x;
    const int n0 = b << BIN_SHIFT;
    const int n1 = min(n0 + BIN_R, N);
    const int nn = n1 - n0;
    const int e0 = bb[b];
    const int e1 = bb[b + 1];

    // stage W1 fragments (independent of everything else)
    for (int ii = tid; ii < INDIM * FEAT; ii += 1024) {
        int k = ii >> 6, n = ii & 63;
        int ct = n >> 4, kc = k >> 5, r = k & 31;
        int owner = ((r >> 3) << 4) | (n & 15);
        wf[(((ct << 2) | kc) * 64 + owner) * 8 + (r & 7)] = (short)f2bf(W1[ii]);
    }
    if (b == 0 && tid >= 512 && tid < 520) {      // zero row N of A
        uint4 z; z.x = 0; z.y = 0; z.z = 0; z.w = 0;
        *reinterpret_cast<uint4*>(A + (long)N * FEAT + (tid - 512) * 8) = z;
    }

    for (int i = tid; i < nn; i += 1024) cnt[i] = 0;
    __syncthreads();
    for (int i = e0 + tid; i < e1; i += 1024) {
        atomicAdd(&cnt[pairs[i] & (BIN_R - 1)], 1);
    }
    __syncthreads();

    const int i0 = 2 * tid;
    int c0 = 0, c1 = 0;
    if (tid < 256) {
        c0 = (i0     < nn) ? cnt[i0]     : 0;
        c1 = (i0 + 1 < nn) ? cnt[i0 + 1] : 0;
        ssum[tid] = c0 + c1;
    }
    __syncthreads();
    for (int d = 1; d < 256; d <<= 1) {
        int t = 0;
        if (tid < 256 && tid >= d) t = ssum[tid - d];
        __syncthreads();
        if (tid < 256) ssum[tid] += t;
        __syncthreads();
    }
    if (tid < 256) {
        int excl = ssum[tid] - (c0 + c1);
        if (i0 < nn) {
            cur[i0] = e0 + excl;
            rp[n0 + i0] = e0 + excl;
            dis[n0 + i0] = rsqrtf((float)c0 + 1.0f);
        }
        if (i0 + 1 < nn) {
            cur[i0 + 1] = e0 + excl + c0;
            rp[n0 + i0 + 1] = e0 + excl + c0;
            dis[n0 + i0 + 1] = rsqrtf((float)c1 + 1.0f);
        }
    }
    __syncthreads();

    for (int i = e0 + tid; i < e1; i += 1024) {
        unsigned p = pairs[i];
        int pos = atomicAdd(&cur[p & (BIN_R - 1)], 1);
        col[pos] = (int)(p >> BIN_SHIFT);
    }
    __syncthreads();

    // ---- gemm1 phase: 16 waves x 32 rows, MFMA 16x16x32 bf16 ----
    const int lane = tid & 63;
    const int w = tid >> 6;
    const int m = lane & 15, q = lane >> 4;
    #pragma unroll
    for (int t = 0; t < 2; ++t) {
        int lrow = w * 32 + t * 16 + m;
        int gr = n0 + lrow;
        int rl = gr < N ? gr : (N - 1);
        const float* xp = x + (long)rl * INDIM + q * 8;
        f32x4 acc[4] = {{0,0,0,0},{0,0,0,0},{0,0,0,0},{0,0,0,0}};
        #pragma unroll
        for (int kc = 0; kc < 4; ++kc) {
            float4 v0 = *reinterpret_cast<const float4*>(xp + kc * 32);
            float4 v1 = *reinterpret_cast<const float4*>(xp + kc * 32 + 4);
            short8 a;
            a[0]=(short)f2bf(v0.x); a[1]=(short)f2bf(v0.y); a[2]=(short)f2bf(v0.z); a[3]=(short)f2bf(v0.w);
            a[4]=(short)f2bf(v1.x); a[5]=(short)f2bf(v1.y); a[6]=(short)f2bf(v1.z); a[7]=(short)f2bf(v1.w);
            #pragma unroll
            for (int ct = 0; ct < 4; ++ct) {
                short8 bf = *reinterpret_cast<const short8*>(&wf[(((ct << 2) | kc) * 64 + lane) * 8]);
                acc[ct] = __builtin_amdgcn_mfma_f32_16x16x32_bf16(a, bf, acc[ct], 0, 0, 0);
            }
        }
        #pragma unroll
        for (int reg = 0; reg < 4; ++reg) {
            int ld = w * 32 + t * 16 + q * 4 + reg;
            if (ld < nn) {
                float sc = rsqrtf((float)cnt[ld] + 1.0f);
                int row = n0 + ld;
                #pragma unroll
                for (int ct = 0; ct < 4; ++ct)
                    A[(long)row * FEAT + ct * 16 + m] = f2bf(acc[ct][reg] * sc);
            }
        }
    }
}

// plain binB2 (fallback tiers)
__global__ __launch_bounds__(1024) void k_binB2(const unsigned* __restrict__ pairs,
                                                const int* __restrict__ bb,
                                                int* __restrict__ rp,
                                                int* __restrict__ col,
                                                float* __restrict__ dis, int N) {
    __shared__ int cnt[BIN_R];
    __shared__ int cur[BIN_R];
    __shared__ int ssum[256];
    const int tid = threadIdx.x;
    const int b = blockIdx.x;
    const int n0 = b << BIN_SHIFT;
    const int n1 = min(n0 + BIN_R, N);
    const int nn = n1 - n0;
    const int e0 = bb[b];
    const int e1 = bb[b + 1];

    for (int i = tid; i < nn; i += 1024) cnt[i] = 0;
    __syncthreads();
    for (int i = e0 + tid; i < e1; i += 1024) {
        atomicAdd(&cnt[pairs[i] & (BIN_R - 1)], 1);
    }
    __syncthreads();

    const int i0 = 2 * tid;
    int c0 = 0, c1 = 0;
    if (tid < 256) {
        c0 = (i0     < nn) ? cnt[i0]     : 0;
        c1 = (i0 + 1 < nn) ? cnt[i0 + 1] : 0;
        ssum[tid] = c0 + c1;
    }
    __syncthreads();
    for (int d = 1; d < 256; d <<= 1) {
        int t = 0;
        if (tid < 256 && tid >= d) t = ssum[tid - d];
        __syncthreads();
        if (tid < 256) ssum[tid] += t;
        __syncthreads();
    }
    if (tid < 256) {
        int excl = ssum[tid] - (c0 + c1);
        if (i0 < nn) {
            cur[i0] = e0 + excl;
            rp[n0 + i0] = e0 + excl;
            dis[n0 + i0] = rsqrtf((float)c0 + 1.0f);
        }
        if (i0 + 1 < nn) {
            cur[i0 + 1] = e0 + excl + c0;
            rp[n0 + i0 + 1] = e0 + excl + c0;
            dis[n0 + i0 + 1] = rsqrtf((float)c1 + 1.0f);
        }
    }
    __syncthreads();

    for (int i = e0 + tid; i < e1; i += 1024) {
        unsigned p = pairs[i];
        int pos = atomicAdd(&cur[p & (BIN_R - 1)], 1);
        col[pos] = (int)(p >> BIN_SHIFT);
    }
}

// ==================== fallback CSR build (proven path) ====================

__global__ __launch_bounds__(256) void k_hist(const int* __restrict__ dst,
                                              int* __restrict__ cntE, int E, int N) {
    int e = blockIdx.x * 256 + threadIdx.x;
    if (e < E) {
        int d = dst[e];
        if ((unsigned)d < (unsigned)N) atomicAdd(&cntE[d], 1);
    }
}
__global__ __launch_bounds__(256) void k_dis(const int* __restrict__ cntE,
                                             float* __restrict__ dis, int N) {
    int i = blockIdx.x * 256 + threadIdx.x;
    if (i < N) dis[i] = rsqrtf((float)cntE[i] + 1.0f);
}
__global__ __launch_bounds__(SCAN_BS) void k_scan1(const int* __restrict__ c,
                                                   int* __restrict__ rp,
                                                   int* __restrict__ ptot, int N) {
    __shared__ int lds[SCAN_BS];
    const int base = blockIdx.x * SCAN_CHUNK;
    const int tb = base + threadIdx.x * SCAN_ELEMS;
    int vals[SCAN_ELEMS];
    int s = 0;
    #pragma unroll
    for (int k = 0; k < SCAN_ELEMS; ++k) {
        int idx = tb + k;
        int v = (idx < N) ? c[idx] : 0;
        vals[k] = s;
        s += v;
    }
    lds[threadIdx.x] = s;
    __syncthreads();
    for (int d = 1; d < SCAN_BS; d <<= 1) {
        int v = (threadIdx.x >= d) ? lds[threadIdx.x - d] : 0;
        __syncthreads();
        lds[threadIdx.x] += v;
        __syncthreads();
    }
    int toff = (threadIdx.x == 0) ? 0 : lds[threadIdx.x - 1];
    #pragma unroll
    for (int k = 0; k < SCAN_ELEMS; ++k) {
        int idx = tb + k;
        if (idx < N) rp[idx] = toff + vals[k];
    }
    if (threadIdx.x == SCAN_BS - 1) ptot[blockIdx.x] = lds[SCAN_BS - 1];
}
__global__ __launch_bounds__(1024) void k_scan2(int* __restrict__ ptot,
                                                int* __restrict__ poff,
                                                int* __restrict__ rpN, int nb) {
    __shared__ int lds[1024];
    int tid = threadIdx.x;
    lds[tid] = (tid < nb) ? ptot[tid] : 0;
    __syncthreads();
    for (int d = 1; d < 1024; d <<= 1) {
        int v = (tid >= d) ? lds[tid - d] : 0;
        __syncthreads();
        lds[tid] += v;
        __syncthreads();
    }
    if (tid < nb) poff[tid] = (tid == 0) ? 0 : lds[tid - 1];
    if (tid == nb - 1) *rpN = lds[tid];
}
__global__ __launch_bounds__(SCAN_BS) void k_scan3(int* __restrict__ rp,
                                                   const int* __restrict__ poff, int N) {
    int off = poff[blockIdx.x];
    const int tb = blockIdx.x * SCAN_CHUNK + threadIdx.x * SCAN_ELEMS;
    #pragma unroll
    for (int k = 0; k < SCAN_ELEMS; ++k) {
        int idx = tb + k;
        if (idx < N) rp[idx] += off;
    }
}
__global__ __launch_bounds__(256) void k_fill(const int* __restrict__ src,
                                              const int* __restrict__ dst,
                                              const int* __restrict__ rp,
                                              int* __restrict__ tmp,
                                              int* __restrict__ col, int E, int N) {
    int e = blockIdx.x * 256 + threadIdx.x;
    if (e >= E) return;
    int s = src[e], d = dst[e];
    if ((unsigned)s >= (unsigned)N) s = 0;
    if ((unsigned)d >= (unsigned)N) return;
    int r = atomicAdd(&tmp[d], 1);
    col[rp[d] + r] = s;
}

__global__ __launch_bounds__(256) void k_ucnt(const int* __restrict__ uidx,
                                              float* __restrict__ cntf, int N) {
    int i = blockIdx.x * 256 + threadIdx.x;
    if (i < N) {
        int u = uidx[i];
        if ((unsigned)u < (unsigned)N) atomicAdd(&cntf[u], 1.0f);
    }
}

// ==================== MFMA GEMMs (fallback tiers) ====================

__global__ __launch_bounds__(256) void k_gemm1(const float* __restrict__ x,
                                               const float* __restrict__ W,
                                               const float* __restrict__ scale,
                                               unsigned short* __restrict__ out, int N) {
    __shared__ short wf[4 * 4 * 64 * 8];
    const int tid = threadIdx.x;
    if (blockIdx.x == 0 && tid < 8) {
        uint4 z; z.x = 0; z.y = 0; z.z = 0; z.w = 0;
        *reinterpret_cast<uint4*>(out + (long)N * FEAT + tid * 8) = z;
    }
    for (int i = tid; i < INDIM * FEAT; i += 256) {
        int k = i >> 6, n = i & 63;
        int ct = n >> 4, kc = k >> 5, r = k & 31;
        int owner = ((r >> 3) << 4) | (n & 15);
        wf[(((ct << 2) | kc) * 64 + owner) * 8 + (r & 7)] = (short)f2bf(W[i]);
    }
    __syncthreads();

    const int lane = tid & 63;
    const int m = lane & 15, q = lane >> 4;
    const int row0 = blockIdx.x * 64 + (tid >> 6) * 16;

    short8 bfr[4][4];
    #pragma unroll
    for (int ct = 0; ct < 4; ++ct)
        #pragma unroll
        for (int kc = 0; kc < 4; ++kc)
            bfr[ct][kc] = *reinterpret_cast<const short8*>(&wf[(((ct << 2) | kc) * 64 + lane) * 8]);

    int gr = row0 + m;
    int rl = gr < N ? gr : (N - 1);
    const float* xp = x + (long)rl * INDIM + q * 8;

    f32x4 acc[4] = {{0,0,0,0},{0,0,0,0},{0,0,0,0},{0,0,0,0}};
    #pragma unroll
    for (int kc = 0; kc < 4; ++kc) {
        float4 v0 = *reinterpret_cast<const float4*>(xp + kc * 32);
        float4 v1 = *reinterpret_cast<const float4*>(xp + kc * 32 + 4);
        short8 a;
        a[0]=(short)f2bf(v0.x); a[1]=(short)f2bf(v0.y); a[2]=(short)f2bf(v0.z); a[3]=(short)f2bf(v0.w);
        a[4]=(short)f2bf(v1.x); a[5]=(short)f2bf(v1.y); a[6]=(short)f2bf(v1.z); a[7]=(short)f2bf(v1.w);
        #pragma unroll
        for (int ct = 0; ct < 4; ++ct)
            acc[ct] = __builtin_amdgcn_mfma_f32_16x16x32_bf16(a, bfr[ct][kc], acc[ct], 0, 0, 0);
    }

    #pragma unroll
    for (int reg = 0; reg < 4; ++reg) {
        int row = row0 + q * 4 + reg;
        if (row < N) {
            float sc = scale[row];
            #pragma unroll
            for (int ct = 0; ct < 4; ++ct)
                out[(long)row * FEAT + ct * 16 + m] = f2bf(acc[ct][reg] * sc);
        }
    }
}

__global__ __launch_bounds__(256) void k_gemm2(const unsigned short* __restrict__ h,
                                               const float* __restrict__ W,
                                               const float* __restrict__ scale,
                                               unsigned short* __restrict__ out, int N) {
    __shared__ short wf[4 * 2 * 64 * 8];
    const int tid = threadIdx.x;
    if (blockIdx.x == 0 && tid < 8) {
        uint4 z; z.x = 0; z.y = 0; z.z = 0; z.w = 0;
        *reinterpret_cast<uint4*>(out + (long)N * FEAT + tid * 8) = z;
    }
    for (int i = tid; i < FEAT * FEAT; i += 256) {
        int k = i >> 6, n = i & 63;
        int ct = n >> 4, kc = k >> 5, r = k & 31;
        int owner = ((r >> 3) << 4) | (n & 15);
        wf[(((ct << 1) | kc) * 64 + owner) * 8 + (r & 7)] = (short)f2bf(W[i]);
    }
    __syncthreads();

    const int lane = tid & 63;
    const int m = lane & 15, q = lane >> 4;
    const int row0 = blockIdx.x * 64 + (tid >> 6) * 16;

    short8 bfr[4][2];
    #pragma unroll
    for (int ct = 0; ct < 4; ++ct)
        #pragma unroll
        for (int kc = 0; kc < 2; ++kc)
            bfr[ct][kc] = *reinterpret_cast<const short8*>(&wf[(((ct << 1) | kc) * 64 + lane) * 8]);

    int gr = row0 + m;
    int rl = gr < N ? gr : (N - 1);
    const unsigned short* hp = h + (long)rl * FEAT + q * 8;

    f32x4 acc[4] = {{0,0,0,0},{0,0,0,0},{0,0,0,0},{0,0,0,0}};
    #pragma unroll
    for (int kc = 0; kc < 2; ++kc) {
        short8 a = *reinterpret_cast<const short8*>(hp + kc * 32);
        #pragma unroll
        for (int ct = 0; ct < 4; ++ct)
            acc[ct] = __builtin_amdgcn_mfma_f32_16x16x32_bf16(a, bfr[ct][kc], acc[ct], 0, 0, 0);
    }

    #pragma unroll
    for (int reg = 0; reg < 4; ++reg) {
        int row = row0 + q * 4 + reg;
        if (row < N) {
            float sc = scale[row];
            #pragma unroll
            for (int ct = 0; ct < 4; ++ct)
                out[(long)row * FEAT + ct * 16 + m] = f2bf(acc[ct][reg] * sc);
        }
    }
}

// ==================== pull aggregation: 4 nodes/wave, 8 gathers in flight =====
// lane = 16*p + 8*s + ol (p = node 0..3, s = slot-parity 0..1, ol = octet).
// Each iteration covers 16 edges/node; 8 independent uint4 gathers in flight.
// Dummy slots read zero row N of A (L1-hot, adds 0). Reduce: one shfl_xor(8).

#define ACC8(r)                                                                  \
    a0 += bf2f((unsigned short)(r).x);                                           \
    a1 += bf2f((unsigned short)((r).x >> 16));                                   \
    a2 += bf2f((unsigned short)(r).y);                                           \
    a3 += bf2f((unsigned short)((r).y >> 16));                                   \
    a4 += bf2f((unsigned short)(r).z);                                           \
    a5 += bf2f((unsigned short)((r).z >> 16));                                   \
    a6 += bf2f((unsigned short)(r).w);                                           \
    a7 += bf2f((unsigned short)((r).w >> 16));

#define AGG_BODY(SELF_INIT)                                                      \
    const int lane = threadIdx.x & 63;                                           \
    const int wv = threadIdx.x >> 6;                                             \
    const int p  = lane >> 4;                                                    \
    const int s  = (lane >> 3) & 1;                                              \
    const int ol = lane & 7;                                                     \
    const int i  = blockIdx.x * 16 + wv * 4 + p;                                 \
    const bool valid = (i < N);                                                  \
    const int jb = valid ? rp[i] : 0;                                            \
    const int je = valid ? rp[i + 1] : 0;                                        \
    float a0=0.f,a1=0.f,a2=0.f,a3=0.f,a4=0.f,a5=0.f,a6=0.f,a7=0.f;               \
    if (valid && s == 0) { SELF_INIT }                                           \
    for (int j0 = jb; j0 < je; j0 += 16) {                                       \
        int j1 = j0 + s;                                                         \
        int c1 = (j1      < je) ? col[j1]      : N;                              \
        int c2 = (j1 + 2  < je) ? col[j1 + 2]  : N;                              \
        int c3 = (j1 + 4  < je) ? col[j1 + 4]  : N;                              \
        int c4 = (j1 + 6  < je) ? col[j1 + 6]  : N;                              \
        int c5 = (j1 + 8  < je) ? col[j1 + 8]  : N;                              \
        int c6 = (j1 + 10 < je) ? col[j1 + 10] : N;                              \
        int c7 = (j1 + 12 < je) ? col[j1 + 12] : N;                              \
        int c8 = (j1 + 14 < je) ? col[j1 + 14] : N;                              \
        uint4 r1 = *reinterpret_cast<const uint4*>(A + (long)c1 * FEAT + 8 * ol);\
        uint4 r2 = *reinterpret_cast<const uint4*>(A + (long)c2 * FEAT + 8 * ol);\
        uint4 r3 = *reinterpret_cast<const uint4*>(A + (long)c3 * FEAT + 8 * ol);\
        uint4 r4 = *reinterpret_cast<const uint4*>(A + (long)c4 * FEAT + 8 * ol);\
        uint4 r5 = *reinterpret_cast<const uint4*>(A + (long)c5 * FEAT + 8 * ol);\
        uint4 r6 = *reinterpret_cast<const uint4*>(A + (long)c6 * FEAT + 8 * ol);\
        uint4 r7 = *reinterpret_cast<const uint4*>(A + (long)c7 * FEAT + 8 * ol);\
        uint4 r8 = *reinterpret_cast<const uint4*>(A + (long)c8 * FEAT + 8 * ol);\
        ACC8(r1)                                                                 \
        ACC8(r2)                                                                 \
        ACC8(r3)                                                                 \
        ACC8(r4)                                                                 \
        ACC8(r5)                                                                 \
        ACC8(r6)                                                                 \
        ACC8(r7)                                                                 \
        ACC8(r8)                                                                 \
    }                                                                            \
    a0 += __shfl_xor(a0, 8);  a1 += __shfl_xor(a1, 8);                           \
    a2 += __shfl_xor(a2, 8);  a3 += __shfl_xor(a3, 8);                           \
    a4 += __shfl_xor(a4, 8);  a5 += __shfl_xor(a5, 8);                           \
    a6 += __shfl_xor(a6, 8);  a7 += __shfl_xor(a7, 8);

// mid-tier fallback: agg1 writes relu(di*sum + b) as PACKED BF16 to Hb
__global__ __launch_bounds__(256) void k_agg1(const unsigned short* __restrict__ A,
                                              const int* __restrict__ rp,
                                              const int* __restrict__ col,
                                              const float* __restrict__ dis,
                                              const float* __restrict__ bias,
                                              unsigned short* __restrict__ H, int N) {
    AGG_BODY(
        uint4 rv = *reinterpret_cast<const uint4*>(A + (long)i * FEAT + 8 * ol);
        a0 = bf2f((unsigned short)rv.x); a1 = bf2f((unsigned short)(rv.x >> 16));
        a2 = bf2f((unsigned short)rv.y); a3 = bf2f((unsigned short)(rv.y >> 16));
        a4 = bf2f((unsigned short)rv.z); a5 = bf2f((unsigned short)(rv.z >> 16));
        a6 = bf2f((unsigned short)rv.w); a7 = bf2f((unsigned short)(rv.w >> 16));
    )
    if (s == 0 && valid) {
        float di = dis[i];
        float4 b4a = *reinterpret_cast<const float4*>(bias + 8 * ol);
        float4 b4b = *reinterpret_cast<const float4*>(bias + 8 * ol + 4);
        uint4 o;
        o.x = (unsigned)f2bf(fmaxf(fmaf(di, a0, b4a.x), 0.f))
            | ((unsigned)f2bf(fmaxf(fmaf(di, a1, b4a.y), 0.f)) << 16);
        o.y = (unsigned)f2bf(fmaxf(fmaf(di, a2, b4a.z), 0.f))
            | ((unsigned)f2bf(fmaxf(fmaf(di, a3, b4a.w), 0.f)) << 16);
        o.z = (unsigned)f2bf(fmaxf(fmaf(di, a4, b4b.x), 0.f))
            | ((unsigned)f2bf(fmaxf(fmaf(di, a5, b4b.y), 0.f)) << 16);
        o.w = (unsigned)f2bf(fmaxf(fmaf(di, a6, b4b.z), 0.f))
            | ((unsigned)f2bf(fmaxf(fmaf(di, a7, b4b.w), 0.f)) << 16);
        *reinterpret_cast<uint4*>(H + (long)i * FEAT + 8 * ol) = o;
    }
}

// FUSED agg1+gemm2: block = 16 nodes = one 16x64 MFMA tile.
__global__ __launch_bounds__(256) void k_agg1f(const unsigned short* __restrict__ A,
                                               const int* __restrict__ rp,
                                               const int* __restrict__ col,
                                               const float* __restrict__ dis,
                                               const float* __restrict__ bias,
                                               const float* __restrict__ W2,
                                               unsigned short* __restrict__ A2, int N) {
    __shared__ short wf[4 * 2 * 64 * 8];       // W2 fragments, 8 KB
    __shared__ unsigned short hh[16][72];      // h1 bf16, padded rows
    __shared__ float dl[16];
    const int tid = threadIdx.x;
    for (int ii = tid; ii < FEAT * FEAT; ii += 256) {
        int k = ii >> 6, n = ii & 63;
        int ct = n >> 4, kc = k >> 5, r = k & 31;
        int owner = ((r >> 3) << 4) | (n & 15);
        wf[(((ct << 1) | kc) * 64 + owner) * 8 + (r & 7)] = (short)f2bf(W2[ii]);
    }
    const int base16 = blockIdx.x * 16;
    if (tid < 16) {
        int node = base16 + tid;
        dl[tid] = (node < N) ? dis[node] : 0.f;
    }
    if (blockIdx.x == 0 && tid >= 32 && tid < 40) {
        uint4 z; z.x = 0; z.y = 0; z.z = 0; z.w = 0;
        *reinterpret_cast<uint4*>(A2 + (long)N * FEAT + (tid - 32) * 8) = z;
    }

    AGG_BODY(
        uint4 rv = *reinterpret_cast<const uint4*>(A + (long)i * FEAT + 8 * ol);
        a0 = bf2f((unsigned short)rv.x); a1 = bf2f((unsigned short)(rv.x >> 16));
        a2 = bf2f((unsigned short)rv.y); a3 = bf2f((unsigned short)(rv.y >> 16));
        a4 = bf2f((unsigned short)rv.z); a5 = bf2f((unsigned short)(rv.z >> 16));
        a6 = bf2f((unsigned short)rv.w); a7 = bf2f((unsigned short)(rv.w >> 16));
    )
    if (s == 0 && valid) {
        float di = dis[i];
        float4 b4a = *reinterpret_cast<const float4*>(bias + 8 * ol);
        float4 b4b = *reinterpret_cast<const float4*>(bias + 8 * ol + 4);
        uint4 o;
        o.x = (unsigned)f2bf(fmaxf(fmaf(di, a0, b4a.x), 0.f))
            | ((unsigned)f2bf(fmaxf(fmaf(di, a1, b4a.y), 0.f)) << 16);
        o.y = (unsigned)f2bf(fmaxf(fmaf(di, a2, b4a.z), 0.f))
            | ((unsigned)f2bf(fmaxf(fmaf(di, a3, b4a.w), 0.f)) << 16);
        o.z = (unsigned)f2bf(fmaxf(fmaf(di, a4, b4b.x), 0.f))
            | ((unsigned)f2bf(fmaxf(fmaf(di, a5, b4b.y), 0.f)) << 16);
        o.w = (unsigned)f2bf(fmaxf(fmaf(di, a6, b4b.z), 0.f))
            | ((unsigned)f2bf(fmaxf(fmaf(di, a7, b4b.w), 0.f)) << 16);
        *reinterpret_cast<uint4*>(&hh[wv * 4 + p][8 * ol]) = o;
    }
    __syncthreads();

    const int m = lane & 15, q = lane >> 4;
    short8 af0 = *reinterpret_cast<const short8*>(&hh[m][q * 8]);        // kc=0
    short8 af1 = *reinterpret_cast<const short8*>(&hh[m][32 + q * 8]);   // kc=1
    short8 bf0 = *reinterpret_cast<const short8*>(&wf[(((wv << 1) | 0) * 64 + lane) * 8]);
    short8 bf1 = *reinterpret_cast<const short8*>(&wf[(((wv << 1) | 1) * 64 + lane) * 8]);
    f32x4 acc = {0, 0, 0, 0};
    acc = __builtin_amdgcn_mfma_f32_16x16x32_bf16(af0, bf0, acc, 0, 0, 0);
    acc = __builtin_amdgcn_mfma_f32_16x16x32_bf16(af1, bf1, acc, 0, 0, 0);
    #pragma unroll
    for (int reg = 0; reg < 4; ++reg) {
        int node = q * 4 + reg;
        int row = base16 + node;
        if (row < N)
            A2[(long)row * FEAT + wv * 16 + m] = f2bf(acc[reg] * dl[node]);
    }
}

// agg2 + scatter: LDS-stage the 4 rows, then ONE full-wave 64-lane contiguous
// atomicAdd per node (256B/instr -> TCC merges to full-line RMW).
__global__ __launch_bounds__(256) void k_agg2s(const unsigned short* __restrict__ A,
                                               const int* __restrict__ rp,
                                               const int* __restrict__ col,
                                               const float* __restrict__ dis,
                                               const float* __restrict__ bias,
                                               const int* __restrict__ uidx,
                                               const float* __restrict__ cntf,
                                               float* __restrict__ S, int N) {
    __shared__ float sbuf[4][4][65];
    AGG_BODY(
        uint4 rv = *reinterpret_cast<const uint4*>(A + (long)i * FEAT + 8 * ol);
        a0 = bf2f((unsigned short)rv.x); a1 = bf2f((unsigned short)(rv.x >> 16));
        a2 = bf2f((unsigned short)rv.y); a3 = bf2f((unsigned short)(rv.y >> 16));
        a4 = bf2f((unsigned short)rv.z); a5 = bf2f((unsigned short)(rv.z >> 16));
        a6 = bf2f((unsigned short)rv.w); a7 = bf2f((unsigned short)(rv.w >> 16));
    )
    if (s == 0) {
        float* dl = &sbuf[wv][p][8 * ol];
        dl[0] = a0; dl[1] = a1; dl[2] = a2; dl[3] = a3;
        dl[4] = a4; dl[5] = a5; dl[6] = a6; dl[7] = a7;
    }
    __syncthreads();
    const int base4 = blockIdx.x * 16 + wv * 4;
    const float bl = bias[lane];
    #pragma unroll
    for (int pp = 0; pp < 4; ++pp) {
        int node = base4 + pp;
        if (node < N) {
            int u = uidx[node];
            if ((unsigned)u < (unsigned)N) {
                float c = cntf[u];
                float wgt = (c > 0.f) ? (1.0f / c) : 0.f;
                float di = dis[node];
                float v = sbuf[wv][pp][lane];
                atomicAdd(&S[(long)u * FEAT + lane], wgt * fmaf(di, v, bl));
            }
        }
    }
}

extern "C" void kernel_launch(void* const* d_in, const int* in_sizes, int n_in,
                              void* d_out, int out_size, void* d_ws, size_t ws_size,
                              hipStream_t stream) {
    const float* x   = (const float*)d_in[0];
    const int* edge  = (const int*)d_in[1];
    const int* uidx  = (const int*)d_in[2];
    const float* W1  = (const float*)d_in[3];
    const float* b1  = (const float*)d_in[4];
    const float* W2  = (const float*)d_in[5];
    const float* b2  = (const float*)d_in[6];
    float* out       = (float*)d_out;

    const int N = in_sizes[2];       // 100000
    const int E = in_sizes[1] / 2;   // 1600000
    const int* src = edge;
    const int* dst = edge + E;

    const size_t fbuf = (size_t)N * FEAT * sizeof(float);
    const size_t abuf = (size_t)(N + 1) * FEAT * sizeof(unsigned short); // +zero row
    const int gE   = (E + 255) / 256;
    const int gN   = (N + 255) / 256;
    const int gN16 = (N + 15) / 16;
    const int gG   = (N + 63) / 64;
    const int gBH  = (E + BH_TILE - 1) / BH_TILE;
    const int nbScan = (N + SCAN_CHUNK - 1) / SCAN_CHUNK;
    const int KB = (N + BIN_R - 1) >> BIN_SHIFT;            // 196

    auto align256 = [](size_t v) { return (v + 255) & ~(size_t)255; };

    char* w = (char*)d_ws;
    size_t o = 0;
    float* dis  = (float*)(w + o); o = align256(o + (size_t)N * 4);
    float* cntf = (float*)(w + o); o = align256(o + (size_t)N * 4);
    int*   cntE = (int*)  (w + o); o = align256(o + (size_t)N * 4);   // gbc+done alias; adjacent to cntf
    int*   rp   = (int*)  (w + o); o = align256(o + (size_t)(N + 1) * 4);
    int*   ptot = (int*)  (w + o); o = align256(o + (size_t)1024 * 4); // bb aliases
    int*   poff = (int*)  (w + o); o = align256(o + (size_t)1024 * 4); // bcur aliases
    int*   col  = (int*)  (w + o); o = align256(o + (size_t)E * 4);
    size_t apsz = (size_t)E * 4 > abuf ? (size_t)E * 4 : abuf;
    char*  Ap   = w + o;           o = align256(o + apsz);            // pairs -> A2 (tier1) / A (tier2)
    const size_t need_base = o;
    unsigned short* Asep = (unsigned short*)(w + o); o = align256(o + abuf);
    const size_t need_fused = o;

    int* gbc  = cntE;
    unsigned* done = (unsigned*)(gbc + KB);
    int* bb   = ptot;
    int* bcur = poff;
    unsigned* pairs = (unsigned*)Ap;
    unsigned short* A2t1 = (unsigned short*)Ap;  // tier1: A2 over dead pairs
    unsigned short* At2  = (unsigned short*)Ap;  // tier2: A over dead pairs
    unsigned short* Hb = (unsigned short*)out;   // tier2: bf16 H in out

    const bool binOK = (KB <= 256) && (N <= (1 << (32 - BIN_SHIFT - 1))) && (KB + 1 <= N);
    const long NF4 = (long)N * FEAT / 4;

    if (ws_size >= need_fused && binOK) {
        // zero cntf (N floats) + gbc (KB ints) + done in one shot (adjacent)
        size_t zspan = (size_t)((char*)gbc - (char*)cntf) + (size_t)(KB + 1) * 4;
        hipMemsetAsync(cntf, 0, zspan, stream);
        k_bhist2<<<gBH, 256, 0, stream>>>(dst, gbc, uidx, cntf, (uint4*)out, NF4,
                                          done, bb, bcur, rp + N, E, N, KB);
        k_binA  <<<(E + BIN_TILE - 1) / BIN_TILE, 256, 0, stream>>>(src, dst, bcur, pairs, E, N, KB);
        k_binB2g<<<KB, 1024, 0, stream>>>(pairs, bb, rp, col, dis, x, W1, Asep, N);
        k_agg1f <<<gN16, 256, 0, stream>>>(Asep, rp, col, dis, b1, W2, A2t1, N);
        k_agg2s <<<gN16, 256, 0, stream>>>(A2t1, rp, col, dis, b2, uidx, cntf, out, N);
    } else if (ws_size >= need_base && binOK) {
        size_t zspan = (size_t)((char*)gbc - (char*)cntf) + (size_t)(KB + 1) * 4;
        hipMemsetAsync(cntf, 0, zspan, stream);
        k_bhist2<<<gBH, 256, 0, stream>>>(dst, gbc, uidx, cntf, (uint4*)nullptr, 0,
                                          done, bb, bcur, rp + N, E, N, KB);
        k_binA <<<(E + BIN_TILE - 1) / BIN_TILE, 256, 0, stream>>>(src, dst, bcur, pairs, E, N, KB);
        k_binB2<<<KB, 1024, 0, stream>>>(pairs, bb, rp, col, dis, N);

        k_gemm1<<<gG, 256, 0, stream>>>(x, W1, dis, At2, N);
        k_agg1 <<<gN16, 256, 0, stream>>>(At2, rp, col, dis, b1, Hb, N);
        k_gemm2<<<gG, 256, 0, stream>>>(Hb, W2, dis, At2, N);
        hipMemsetAsync(out, 0, fbuf, stream);
        k_agg2s<<<gN16, 256, 0, stream>>>(At2, rp, col, dis, b2, uidx, cntf, out, N);
    } else {
        hipMemsetAsync(cntE, 0, (size_t)N * 4, stream);
        k_hist <<<gE, 256, 0, stream>>>(dst, cntE, E, N);
        k_dis  <<<gN, 256, 0, stream>>>(cntE, dis, N);
        k_scan1<<<nbScan, SCAN_BS, 0, stream>>>(cntE, rp, ptot, N);
        k_scan2<<<1, 1024, 0, stream>>>(ptot, poff, rp + N, nbScan);
        k_scan3<<<nbScan, SCAN_BS, 0, stream>>>(rp, poff, N);
        hipMemsetAsync(cntE, 0, (size_t)N * 4, stream);
        k_fill <<<gE, 256, 0, stream>>>(src, dst, rp, cntE, col, E, N);
        hipMemsetAsync(cntf, 0, (size_t)N * 4, stream);
        k_ucnt <<<gN, 256, 0, stream>>>(uidx, cntf, N);
        k_gemm1<<<gG, 256, 0, stream>>>(x, W1, dis, At2, N);
        k_agg1 <<<gN16, 256, 0, stream>>>(At2, rp, col, dis, b1, Hb, N);
        k_gemm2<<<gG, 256, 0, stream>>>(Hb, W2, dis, At2, N);
        hipMemsetAsync(out, 0, fbuf, stream);
        k_agg2s<<<gN16, 256, 0, stream>>>(At2, rp, col, dis, b2, uidx, cntf, out, N);
    }
}

// Round 7
// 256.931 us; speedup vs baseline: 1.2760x; 1.2760x over previous
//
#include <hip/hip_runtime.h>
#include <hip/hip_bf16.h>

// GCN: h1 = relu(GCNConv(x, W1, b1)); out = scatter_mean(GCNConv(h1, W2, b2), user_idx)
// N=100000, E=1600000, dims 128 -> 64 -> 64. fp32 I/O, int32 indices.
//
// R18 post-mortem: last-block-done bscan fusion regressed bhist 30->98us
// (VALU 0.5%, HBM 4%): __threadfence() on 8-XCD CDNA4 = device-scope L2
// writeback; 782 blocks x 2 fences serialize at the TCC. A 3us helper launch
// beats 782 device fences. R19: revert to fence-free k_bhist + separate
// k_bscan; KEEP binB2g (gemm1 fused into binB2, -1 dispatch, neutral time).
// Agg kernels remain at their verified structural floor (~42.6us each,
// FETCH 86MB = cross-XCD duplication of A; random-gather roofline).

#define FEAT 64
#define INDIM 128

#define SCAN_BS 256
#define SCAN_ELEMS 8
#define SCAN_CHUNK (SCAN_BS * SCAN_ELEMS)

#define BIN_SHIFT 9
#define BIN_R 512
#define BIN_TILE 2048
#define BH_TILE 2048

typedef __attribute__((ext_vector_type(8))) short short8;
typedef __attribute__((ext_vector_type(4))) float f32x4;

__device__ __forceinline__ unsigned short f2bf(float f) {
    unsigned u = __float_as_uint(f);
    unsigned r = u + 0x7FFFu + ((u >> 16) & 1u);
    return (unsigned short)(r >> 16);
}
__device__ __forceinline__ float bf2f(unsigned short v) {
    return __uint_as_float(((unsigned)v) << 16);
}

// ==================== bucket-level CSR build ====================

// histogram + ucnt + optional out-zeroing (NO fences -- see R18 post-mortem)
__global__ __launch_bounds__(256) void k_bhist(const int* __restrict__ dst,
                                               int* __restrict__ gbc,
                                               const int* __restrict__ uidx,
                                               float* __restrict__ cntf,
                                               uint4* __restrict__ outz, long nz4,
                                               int E, int N, int KB) {
    __shared__ int h[256];
    const int tid = threadIdx.x;
    h[tid] = 0;
    __syncthreads();
    const int base = blockIdx.x * BH_TILE;
    #pragma unroll
    for (int t = 0; t < BH_TILE / 256; ++t) {
        int e = base + t * 256 + tid;
        if (e < E) {
            int d = dst[e];
            if ((unsigned)d < (unsigned)N) atomicAdd(&h[d >> BIN_SHIFT], 1);
        }
    }
    int i = blockIdx.x * 256 + tid;
    if (i < N) {
        int u = uidx[i];
        if ((unsigned)u < (unsigned)N) atomicAdd(&cntf[u], 1.0f);
    }
    if (outz) {
        uint4 z; z.x = 0; z.y = 0; z.z = 0; z.w = 0;
        const long stride = (long)gridDim.x * 256;
        for (long idx = (long)blockIdx.x * 256 + tid; idx < nz4; idx += stride)
            outz[idx] = z;
    }
    __syncthreads();
    if (tid < KB && h[tid]) atomicAdd(&gbc[tid], h[tid]);
}

__global__ __launch_bounds__(256) void k_bscan(const int* __restrict__ gbc,
                                               int* __restrict__ bb,
                                               int* __restrict__ bcur,
                                               int* __restrict__ rpN, int KB) {
    __shared__ int lds[256];
    const int tid = threadIdx.x;
    int v = (tid < KB) ? gbc[tid] : 0;
    lds[tid] = v;
    __syncthreads();
    for (int d = 1; d < 256; d <<= 1) {
        int t = (tid >= d) ? lds[tid - d] : 0;
        __syncthreads();
        lds[tid] += t;
        __syncthreads();
    }
    int excl = lds[tid] - v;
    if (tid < KB) { bb[tid] = excl; bcur[tid] = excl; }
    if (tid == 255) { bb[KB] = lds[255]; *rpN = lds[255]; }
}

// tile-reorder edges by bucket; packed (src<<BIN_SHIFT)|local_dst
__global__ __launch_bounds__(256) void k_binA(const int* __restrict__ src,
                                              const int* __restrict__ dst,
                                              int* __restrict__ bcur,
                                              unsigned* __restrict__ pairs,
                                              int E, int N, int KB) {
    __shared__ unsigned lbuf[BIN_TILE];          // 8 KB
    __shared__ unsigned short bkt[BIN_TILE];     // 4 KB
    __shared__ int lcnt[256];
    __shared__ int loff[256];
    __shared__ int lbase[256];
    __shared__ int tot;
    const int tid = threadIdx.x;
    const int base = blockIdx.x * BIN_TILE;

    lcnt[tid] = 0;
    __syncthreads();

    int mys[BIN_TILE / 256], myd[BIN_TILE / 256], myb[BIN_TILE / 256];
    #pragma unroll
    for (int t = 0; t < BIN_TILE / 256; ++t) {
        int e = base + t * 256 + tid;
        int s = 0, d = -1;
        if (e < E) { s = src[e]; d = dst[e]; }
        if ((unsigned)d >= (unsigned)N) d = -1;
        if ((unsigned)s >= (unsigned)N) s = 0;
        mys[t] = s; myd[t] = d;
        myb[t] = (d >= 0) ? (d >> BIN_SHIFT) : -1;
        if (myb[t] >= 0) atomicAdd(&lcnt[myb[t]], 1);
    }
    __syncthreads();

    int v = lcnt[tid];
    loff[tid] = v;
    __syncthreads();
    for (int d = 1; d < 256; d <<= 1) {
        int t2 = (tid >= d) ? loff[tid - d] : 0;
        __syncthreads();
        loff[tid] += t2;
        __syncthreads();
    }
    if (tid == 255) tot = loff[255];
    int excl = loff[tid] - v;
    __syncthreads();
    loff[tid] = excl;
    lcnt[tid] = excl;
    if (tid < KB && v > 0) lbase[tid] = atomicAdd(&bcur[tid], v);
    __syncthreads();

    #pragma unroll
    for (int t = 0; t < BIN_TILE / 256; ++t) {
        if (myb[t] >= 0) {
            int pos = atomicAdd(&lcnt[myb[t]], 1);
            lbuf[pos] = ((unsigned)mys[t] << BIN_SHIFT) | (unsigned)(myd[t] & (BIN_R - 1));
            bkt[pos] = (unsigned short)myb[t];
        }
    }
    __syncthreads();

    const int T = tot;
    for (int i = tid; i < T; i += 256) {
        int b = bkt[i];
        pairs[lbase[b] + (i - loff[b])] = lbuf[i];
    }
}

// FUSED binB2+gemm1: one WG (16 waves) per bucket of 512 nodes.
// Phase A: degrees in LDS -> rp + dis, rank -> col (as binB2).
// Phase B: each wave MFMAs two 16-row tiles of A = rsqrt(cnt+1)*(x@W1).
__global__ __launch_bounds__(1024) void k_binB2g(const unsigned* __restrict__ pairs,
                                                 const int* __restrict__ bb,
                                                 int* __restrict__ rp,
                                                 int* __restrict__ col,
                                                 float* __restrict__ dis,
                                                 const float* __restrict__ x,
                                                 const float* __restrict__ W1,
                                                 unsigned short* __restrict__ A, int N) {
    __shared__ int cnt[BIN_R];
    __shared__ int cur[BIN_R];
    __shared__ int ssum[256];
    __shared__ short wf[4 * 4 * 64 * 8];   // W1 fragments, 16 KB
    const int tid = threadIdx.x;
    const int b = blockIdx.x;
    const int n0 = b << BIN_SHIFT;
    const int n1 = min(n0 + BIN_R, N);
    const int nn = n1 - n0;
    const int e0 = bb[b];
    const int e1 = bb[b + 1];

    for (int ii = tid; ii < INDIM * FEAT; ii += 1024) {
        int k = ii >> 6, n = ii & 63;
        int ct = n >> 4, kc = k >> 5, r = k & 31;
        int owner = ((r >> 3) << 4) | (n & 15);
        wf[(((ct << 2) | kc) * 64 + owner) * 8 + (r & 7)] = (short)f2bf(W1[ii]);
    }
    if (b == 0 && tid >= 512 && tid < 520) {      // zero row N of A
        uint4 z; z.x = 0; z.y = 0; z.z = 0; z.w = 0;
        *reinterpret_cast<uint4*>(A + (long)N * FEAT + (tid - 512) * 8) = z;
    }

    for (int i = tid; i < nn; i += 1024) cnt[i] = 0;
    __syncthreads();
    for (int i = e0 + tid; i < e1; i += 1024) {
        atomicAdd(&cnt[pairs[i] & (BIN_R - 1)], 1);
    }
    __syncthreads();

    const int i0 = 2 * tid;
    int c0 = 0, c1 = 0;
    if (tid < 256) {
        c0 = (i0     < nn) ? cnt[i0]     : 0;
        c1 = (i0 + 1 < nn) ? cnt[i0 + 1] : 0;
        ssum[tid] = c0 + c1;
    }
    __syncthreads();
    for (int d = 1; d < 256; d <<= 1) {
        int t = 0;
        if (tid < 256 && tid >= d) t = ssum[tid - d];
        __syncthreads();
        if (tid < 256) ssum[tid] += t;
        __syncthreads();
    }
    if (tid < 256) {
        int excl = ssum[tid] - (c0 + c1);
        if (i0 < nn) {
            cur[i0] = e0 + excl;
            rp[n0 + i0] = e0 + excl;
            dis[n0 + i0] = rsqrtf((float)c0 + 1.0f);
        }
        if (i0 + 1 < nn) {
            cur[i0 + 1] = e0 + excl + c0;
            rp[n0 + i0 + 1] = e0 + excl + c0;
            dis[n0 + i0 + 1] = rsqrtf((float)c1 + 1.0f);
        }
    }
    __syncthreads();

    for (int i = e0 + tid; i < e1; i += 1024) {
        unsigned p = pairs[i];
        int pos = atomicAdd(&cur[p & (BIN_R - 1)], 1);
        col[pos] = (int)(p >> BIN_SHIFT);
    }
    __syncthreads();

    // ---- gemm1 phase: 16 waves x 32 rows, MFMA 16x16x32 bf16 ----
    const int lane = tid & 63;
    const int w = tid >> 6;
    const int m = lane & 15, q = lane >> 4;
    #pragma unroll
    for (int t = 0; t < 2; ++t) {
        int lrow = w * 32 + t * 16 + m;
        int gr = n0 + lrow;
        int rl = gr < N ? gr : (N - 1);
        const float* xp = x + (long)rl * INDIM + q * 8;
        f32x4 acc[4] = {{0,0,0,0},{0,0,0,0},{0,0,0,0},{0,0,0,0}};
        #pragma unroll
        for (int kc = 0; kc < 4; ++kc) {
            float4 v0 = *reinterpret_cast<const float4*>(xp + kc * 32);
            float4 v1 = *reinterpret_cast<const float4*>(xp + kc * 32 + 4);
            short8 a;
            a[0]=(short)f2bf(v0.x); a[1]=(short)f2bf(v0.y); a[2]=(short)f2bf(v0.z); a[3]=(short)f2bf(v0.w);
            a[4]=(short)f2bf(v1.x); a[5]=(short)f2bf(v1.y); a[6]=(short)f2bf(v1.z); a[7]=(short)f2bf(v1.w);
            #pragma unroll
            for (int ct = 0; ct < 4; ++ct) {
                short8 bf = *reinterpret_cast<const short8*>(&wf[(((ct << 2) | kc) * 64 + lane) * 8]);
                acc[ct] = __builtin_amdgcn_mfma_f32_16x16x32_bf16(a, bf, acc[ct], 0, 0, 0);
            }
        }
        #pragma unroll
        for (int reg = 0; reg < 4; ++reg) {
            int ld = w * 32 + t * 16 + q * 4 + reg;
            if (ld < nn) {
                float sc = rsqrtf((float)cnt[ld] + 1.0f);
                int row = n0 + ld;
                #pragma unroll
                for (int ct = 0; ct < 4; ++ct)
                    A[(long)row * FEAT + ct * 16 + m] = f2bf(acc[ct][reg] * sc);
            }
        }
    }
}

// plain binB2 (fallback tiers)
__global__ __launch_bounds__(1024) void k_binB2(const unsigned* __restrict__ pairs,
                                                const int* __restrict__ bb,
                                                int* __restrict__ rp,
                                                int* __restrict__ col,
                                                float* __restrict__ dis, int N) {
    __shared__ int cnt[BIN_R];
    __shared__ int cur[BIN_R];
    __shared__ int ssum[256];
    const int tid = threadIdx.x;
    const int b = blockIdx.x;
    const int n0 = b << BIN_SHIFT;
    const int n1 = min(n0 + BIN_R, N);
    const int nn = n1 - n0;
    const int e0 = bb[b];
    const int e1 = bb[b + 1];

    for (int i = tid; i < nn; i += 1024) cnt[i] = 0;
    __syncthreads();
    for (int i = e0 + tid; i < e1; i += 1024) {
        atomicAdd(&cnt[pairs[i] & (BIN_R - 1)], 1);
    }
    __syncthreads();

    const int i0 = 2 * tid;
    int c0 = 0, c1 = 0;
    if (tid < 256) {
        c0 = (i0     < nn) ? cnt[i0]     : 0;
        c1 = (i0 + 1 < nn) ? cnt[i0 + 1] : 0;
        ssum[tid] = c0 + c1;
    }
    __syncthreads();
    for (int d = 1; d < 256; d <<= 1) {
        int t = 0;
        if (tid < 256 && tid >= d) t = ssum[tid - d];
        __syncthreads();
        if (tid < 256) ssum[tid] += t;
        __syncthreads();
    }
    if (tid < 256) {
        int excl = ssum[tid] - (c0 + c1);
        if (i0 < nn) {
            cur[i0] = e0 + excl;
            rp[n0 + i0] = e0 + excl;
            dis[n0 + i0] = rsqrtf((float)c0 + 1.0f);
        }
        if (i0 + 1 < nn) {
            cur[i0 + 1] = e0 + excl + c0;
            rp[n0 + i0 + 1] = e0 + excl + c0;
            dis[n0 + i0 + 1] = rsqrtf((float)c1 + 1.0f);
        }
    }
    __syncthreads();

    for (int i = e0 + tid; i < e1; i += 1024) {
        unsigned p = pairs[i];
        int pos = atomicAdd(&cur[p & (BIN_R - 1)], 1);
        col[pos] = (int)(p >> BIN_SHIFT);
    }
}

// ==================== fallback CSR build (proven path) ====================

__global__ __launch_bounds__(256) void k_hist(const int* __restrict__ dst,
                                              int* __restrict__ cntE, int E, int N) {
    int e = blockIdx.x * 256 + threadIdx.x;
    if (e < E) {
        int d = dst[e];
        if ((unsigned)d < (unsigned)N) atomicAdd(&cntE[d], 1);
    }
}
__global__ __launch_bounds__(256) void k_dis(const int* __restrict__ cntE,
                                             float* __restrict__ dis, int N) {
    int i = blockIdx.x * 256 + threadIdx.x;
    if (i < N) dis[i] = rsqrtf((float)cntE[i] + 1.0f);
}
__global__ __launch_bounds__(SCAN_BS) void k_scan1(const int* __restrict__ c,
                                                   int* __restrict__ rp,
                                                   int* __restrict__ ptot, int N) {
    __shared__ int lds[SCAN_BS];
    const int base = blockIdx.x * SCAN_CHUNK;
    const int tb = base + threadIdx.x * SCAN_ELEMS;
    int vals[SCAN_ELEMS];
    int s = 0;
    #pragma unroll
    for (int k = 0; k < SCAN_ELEMS; ++k) {
        int idx = tb + k;
        int v = (idx < N) ? c[idx] : 0;
        vals[k] = s;
        s += v;
    }
    lds[threadIdx.x] = s;
    __syncthreads();
    for (int d = 1; d < SCAN_BS; d <<= 1) {
        int v = (threadIdx.x >= d) ? lds[threadIdx.x - d] : 0;
        __syncthreads();
        lds[threadIdx.x] += v;
        __syncthreads();
    }
    int toff = (threadIdx.x == 0) ? 0 : lds[threadIdx.x - 1];
    #pragma unroll
    for (int k = 0; k < SCAN_ELEMS; ++k) {
        int idx = tb + k;
        if (idx < N) rp[idx] = toff + vals[k];
    }
    if (threadIdx.x == SCAN_BS - 1) ptot[blockIdx.x] = lds[SCAN_BS - 1];
}
__global__ __launch_bounds__(1024) void k_scan2(int* __restrict__ ptot,
                                                int* __restrict__ poff,
                                                int* __restrict__ rpN, int nb) {
    __shared__ int lds[1024];
    int tid = threadIdx.x;
    lds[tid] = (tid < nb) ? ptot[tid] : 0;
    __syncthreads();
    for (int d = 1; d < 1024; d <<= 1) {
        int v = (tid >= d) ? lds[tid - d] : 0;
        __syncthreads();
        lds[tid] += v;
        __syncthreads();
    }
    if (tid < nb) poff[tid] = (tid == 0) ? 0 : lds[tid - 1];
    if (tid == nb - 1) *rpN = lds[tid];
}
__global__ __launch_bounds__(SCAN_BS) void k_scan3(int* __restrict__ rp,
                                                   const int* __restrict__ poff, int N) {
    int off = poff[blockIdx.x];
    const int tb = blockIdx.x * SCAN_CHUNK + threadIdx.x * SCAN_ELEMS;
    #pragma unroll
    for (int k = 0; k < SCAN_ELEMS; ++k) {
        int idx = tb + k;
        if (idx < N) rp[idx] += off;
    }
}
__global__ __launch_bounds__(256) void k_fill(const int* __restrict__ src,
                                              const int* __restrict__ dst,
                                              const int* __restrict__ rp,
                                              int* __restrict__ tmp,
                                              int* __restrict__ col, int E, int N) {
    int e = blockIdx.x * 256 + threadIdx.x;
    if (e >= E) return;
    int s = src[e], d = dst[e];
    if ((unsigned)s >= (unsigned)N) s = 0;
    if ((unsigned)d >= (unsigned)N) return;
    int r = atomicAdd(&tmp[d], 1);
    col[rp[d] + r] = s;
}

__global__ __launch_bounds__(256) void k_ucnt(const int* __restrict__ uidx,
                                              float* __restrict__ cntf, int N) {
    int i = blockIdx.x * 256 + threadIdx.x;
    if (i < N) {
        int u = uidx[i];
        if ((unsigned)u < (unsigned)N) atomicAdd(&cntf[u], 1.0f);
    }
}

// ==================== MFMA GEMMs (fallback tiers) ====================

__global__ __launch_bounds__(256) void k_gemm1(const float* __restrict__ x,
                                               const float* __restrict__ W,
                                               const float* __restrict__ scale,
                                               unsigned short* __restrict__ out, int N) {
    __shared__ short wf[4 * 4 * 64 * 8];
    const int tid = threadIdx.x;
    if (blockIdx.x == 0 && tid < 8) {
        uint4 z; z.x = 0; z.y = 0; z.z = 0; z.w = 0;
        *reinterpret_cast<uint4*>(out + (long)N * FEAT + tid * 8) = z;
    }
    for (int i = tid; i < INDIM * FEAT; i += 256) {
        int k = i >> 6, n = i & 63;
        int ct = n >> 4, kc = k >> 5, r = k & 31;
        int owner = ((r >> 3) << 4) | (n & 15);
        wf[(((ct << 2) | kc) * 64 + owner) * 8 + (r & 7)] = (short)f2bf(W[i]);
    }
    __syncthreads();

    const int lane = tid & 63;
    const int m = lane & 15, q = lane >> 4;
    const int row0 = blockIdx.x * 64 + (tid >> 6) * 16;

    short8 bfr[4][4];
    #pragma unroll
    for (int ct = 0; ct < 4; ++ct)
        #pragma unroll
        for (int kc = 0; kc < 4; ++kc)
            bfr[ct][kc] = *reinterpret_cast<const short8*>(&wf[(((ct << 2) | kc) * 64 + lane) * 8]);

    int gr = row0 + m;
    int rl = gr < N ? gr : (N - 1);
    const float* xp = x + (long)rl * INDIM + q * 8;

    f32x4 acc[4] = {{0,0,0,0},{0,0,0,0},{0,0,0,0},{0,0,0,0}};
    #pragma unroll
    for (int kc = 0; kc < 4; ++kc) {
        float4 v0 = *reinterpret_cast<const float4*>(xp + kc * 32);
        float4 v1 = *reinterpret_cast<const float4*>(xp + kc * 32 + 4);
        short8 a;
        a[0]=(short)f2bf(v0.x); a[1]=(short)f2bf(v0.y); a[2]=(short)f2bf(v0.z); a[3]=(short)f2bf(v0.w);
        a[4]=(short)f2bf(v1.x); a[5]=(short)f2bf(v1.y); a[6]=(short)f2bf(v1.z); a[7]=(short)f2bf(v1.w);
        #pragma unroll
        for (int ct = 0; ct < 4; ++ct)
            acc[ct] = __builtin_amdgcn_mfma_f32_16x16x32_bf16(a, bfr[ct][kc], acc[ct], 0, 0, 0);
    }

    #pragma unroll
    for (int reg = 0; reg < 4; ++reg) {
        int row = row0 + q * 4 + reg;
        if (row < N) {
            float sc = scale[row];
            #pragma unroll
            for (int ct = 0; ct < 4; ++ct)
                out[(long)row * FEAT + ct * 16 + m] = f2bf(acc[ct][reg] * sc);
        }
    }
}

__global__ __launch_bounds__(256) void k_gemm2(const unsigned short* __restrict__ h,
                                               const float* __restrict__ W,
                                               const float* __restrict__ scale,
                                               unsigned short* __restrict__ out, int N) {
    __shared__ short wf[4 * 2 * 64 * 8];
    const int tid = threadIdx.x;
    if (blockIdx.x == 0 && tid < 8) {
        uint4 z; z.x = 0; z.y = 0; z.z = 0; z.w = 0;
        *reinterpret_cast<uint4*>(out + (long)N * FEAT + tid * 8) = z;
    }
    for (int i = tid; i < FEAT * FEAT; i += 256) {
        int k = i >> 6, n = i & 63;
        int ct = n >> 4, kc = k >> 5, r = k & 31;
        int owner = ((r >> 3) << 4) | (n & 15);
        wf[(((ct << 1) | kc) * 64 + owner) * 8 + (r & 7)] = (short)f2bf(W[i]);
    }
    __syncthreads();

    const int lane = tid & 63;
    const int m = lane & 15, q = lane >> 4;
    const int row0 = blockIdx.x * 64 + (tid >> 6) * 16;

    short8 bfr[4][2];
    #pragma unroll
    for (int ct = 0; ct < 4; ++ct)
        #pragma unroll
        for (int kc = 0; kc < 2; ++kc)
            bfr[ct][kc] = *reinterpret_cast<const short8*>(&wf[(((ct << 1) | kc) * 64 + lane) * 8]);

    int gr = row0 + m;
    int rl = gr < N ? gr : (N - 1);
    const unsigned short* hp = h + (long)rl * FEAT + q * 8;

    f32x4 acc[4] = {{0,0,0,0},{0,0,0,0},{0,0,0,0},{0,0,0,0}};
    #pragma unroll
    for (int kc = 0; kc < 2; ++kc) {
        short8 a = *reinterpret_cast<const short8*>(hp + kc * 32);
        #pragma unroll
        for (int ct = 0; ct < 4; ++ct)
            acc[ct] = __builtin_amdgcn_mfma_f32_16x16x32_bf16(a, bfr[ct][kc], acc[ct], 0, 0, 0);
    }

    #pragma unroll
    for (int reg = 0; reg < 4; ++reg) {
        int row = row0 + q * 4 + reg;
        if (row < N) {
            float sc = scale[row];
            #pragma unroll
            for (int ct = 0; ct < 4; ++ct)
                out[(long)row * FEAT + ct * 16 + m] = f2bf(acc[ct][reg] * sc);
        }
    }
}

// ==================== pull aggregation: 4 nodes/wave, 8 gathers in flight =====
// lane = 16*p + 8*s + ol (p = node 0..3, s = slot-parity 0..1, ol = octet).
// Each iteration covers 16 edges/node; 8 independent uint4 gathers in flight.
// Dummy slots read zero row N of A (L1-hot, adds 0). Reduce: one shfl_xor(8).

#define ACC8(r)                                                                  \
    a0 += bf2f((unsigned short)(r).x);                                           \
    a1 += bf2f((unsigned short)((r).x >> 16));                                   \
    a2 += bf2f((unsigned short)(r).y);                                           \
    a3 += bf2f((unsigned short)((r).y >> 16));                                   \
    a4 += bf2f((unsigned short)(r).z);                                           \
    a5 += bf2f((unsigned short)((r).z >> 16));                                   \
    a6 += bf2f((unsigned short)(r).w);                                           \
    a7 += bf2f((unsigned short)((r).w >> 16));

#define AGG_BODY(SELF_INIT)                                                      \
    const int lane = threadIdx.x & 63;                                           \
    const int wv = threadIdx.x >> 6;                                             \
    const int p  = lane >> 4;                                                    \
    const int s  = (lane >> 3) & 1;                                              \
    const int ol = lane & 7;                                                     \
    const int i  = blockIdx.x * 16 + wv * 4 + p;                                 \
    const bool valid = (i < N);                                                  \
    const int jb = valid ? rp[i] : 0;                                            \
    const int je = valid ? rp[i + 1] : 0;                                        \
    float a0=0.f,a1=0.f,a2=0.f,a3=0.f,a4=0.f,a5=0.f,a6=0.f,a7=0.f;               \
    if (valid && s == 0) { SELF_INIT }                                           \
    for (int j0 = jb; j0 < je; j0 += 16) {                                       \
        int j1 = j0 + s;                                                         \
        int c1 = (j1      < je) ? col[j1]      : N;                              \
        int c2 = (j1 + 2  < je) ? col[j1 + 2]  : N;                              \
        int c3 = (j1 + 4  < je) ? col[j1 + 4]  : N;                              \
        int c4 = (j1 + 6  < je) ? col[j1 + 6]  : N;                              \
        int c5 = (j1 + 8  < je) ? col[j1 + 8]  : N;                              \
        int c6 = (j1 + 10 < je) ? col[j1 + 10] : N;                              \
        int c7 = (j1 + 12 < je) ? col[j1 + 12] : N;                              \
        int c8 = (j1 + 14 < je) ? col[j1 + 14] : N;                              \
        uint4 r1 = *reinterpret_cast<const uint4*>(A + (long)c1 * FEAT + 8 * ol);\
        uint4 r2 = *reinterpret_cast<const uint4*>(A + (long)c2 * FEAT + 8 * ol);\
        uint4 r3 = *reinterpret_cast<const uint4*>(A + (long)c3 * FEAT + 8 * ol);\
        uint4 r4 = *reinterpret_cast<const uint4*>(A + (long)c4 * FEAT + 8 * ol);\
        uint4 r5 = *reinterpret_cast<const uint4*>(A + (long)c5 * FEAT + 8 * ol);\
        uint4 r6 = *reinterpret_cast<const uint4*>(A + (long)c6 * FEAT + 8 * ol);\
        uint4 r7 = *reinterpret_cast<const uint4*>(A + (long)c7 * FEAT + 8 * ol);\
        uint4 r8 = *reinterpret_cast<const uint4*>(A + (long)c8 * FEAT + 8 * ol);\
        ACC8(r1)                                                                 \
        ACC8(r2)                                                                 \
        ACC8(r3)                                                                 \
        ACC8(r4)                                                                 \
        ACC8(r5)                                                                 \
        ACC8(r6)                                                                 \
        ACC8(r7)                                                                 \
        ACC8(r8)                                                                 \
    }                                                                            \
    a0 += __shfl_xor(a0, 8);  a1 += __shfl_xor(a1, 8);                           \
    a2 += __shfl_xor(a2, 8);  a3 += __shfl_xor(a3, 8);                           \
    a4 += __shfl_xor(a4, 8);  a5 += __shfl_xor(a5, 8);                           \
    a6 += __shfl_xor(a6, 8);  a7 += __shfl_xor(a7, 8);

// mid-tier fallback: agg1 writes relu(di*sum + b) as PACKED BF16 to Hb
__global__ __launch_bounds__(256) void k_agg1(const unsigned short* __restrict__ A,
                                              const int* __restrict__ rp,
                                              const int* __restrict__ col,
                                              const float* __restrict__ dis,
                                              const float* __restrict__ bias,
                                              unsigned short* __restrict__ H, int N) {
    AGG_BODY(
        uint4 rv = *reinterpret_cast<const uint4*>(A + (long)i * FEAT + 8 * ol);
        a0 = bf2f((unsigned short)rv.x); a1 = bf2f((unsigned short)(rv.x >> 16));
        a2 = bf2f((unsigned short)rv.y); a3 = bf2f((unsigned short)(rv.y >> 16));
        a4 = bf2f((unsigned short)rv.z); a5 = bf2f((unsigned short)(rv.z >> 16));
        a6 = bf2f((unsigned short)rv.w); a7 = bf2f((unsigned short)(rv.w >> 16));
    )
    if (s == 0 && valid) {
        float di = dis[i];
        float4 b4a = *reinterpret_cast<const float4*>(bias + 8 * ol);
        float4 b4b = *reinterpret_cast<const float4*>(bias + 8 * ol + 4);
        uint4 o;
        o.x = (unsigned)f2bf(fmaxf(fmaf(di, a0, b4a.x), 0.f))
            | ((unsigned)f2bf(fmaxf(fmaf(di, a1, b4a.y), 0.f)) << 16);
        o.y = (unsigned)f2bf(fmaxf(fmaf(di, a2, b4a.z), 0.f))
            | ((unsigned)f2bf(fmaxf(fmaf(di, a3, b4a.w), 0.f)) << 16);
        o.z = (unsigned)f2bf(fmaxf(fmaf(di, a4, b4b.x), 0.f))
            | ((unsigned)f2bf(fmaxf(fmaf(di, a5, b4b.y), 0.f)) << 16);
        o.w = (unsigned)f2bf(fmaxf(fmaf(di, a6, b4b.z), 0.f))
            | ((unsigned)f2bf(fmaxf(fmaf(di, a7, b4b.w), 0.f)) << 16);
        *reinterpret_cast<uint4*>(H + (long)i * FEAT + 8 * ol) = o;
    }
}

// FUSED agg1+gemm2: block = 16 nodes = one 16x64 MFMA tile.
__global__ __launch_bounds__(256) void k_agg1f(const unsigned short* __restrict__ A,
                                               const int* __restrict__ rp,
                                               const int* __restrict__ col,
                                               const float* __restrict__ dis,
                                               const float* __restrict__ bias,
                                               const float* __restrict__ W2,
                                               unsigned short* __restrict__ A2, int N) {
    __shared__ short wf[4 * 2 * 64 * 8];       // W2 fragments, 8 KB
    __shared__ unsigned short hh[16][72];      // h1 bf16, padded rows
    __shared__ float dl[16];
    const int tid = threadIdx.x;
    for (int ii = tid; ii < FEAT * FEAT; ii += 256) {
        int k = ii >> 6, n = ii & 63;
        int ct = n >> 4, kc = k >> 5, r = k & 31;
        int owner = ((r >> 3) << 4) | (n & 15);
        wf[(((ct << 1) | kc) * 64 + owner) * 8 + (r & 7)] = (short)f2bf(W2[ii]);
    }
    const int base16 = blockIdx.x * 16;
    if (tid < 16) {
        int node = base16 + tid;
        dl[tid] = (node < N) ? dis[node] : 0.f;
    }
    if (blockIdx.x == 0 && tid >= 32 && tid < 40) {
        uint4 z; z.x = 0; z.y = 0; z.z = 0; z.w = 0;
        *reinterpret_cast<uint4*>(A2 + (long)N * FEAT + (tid - 32) * 8) = z;
    }

    AGG_BODY(
        uint4 rv = *reinterpret_cast<const uint4*>(A + (long)i * FEAT + 8 * ol);
        a0 = bf2f((unsigned short)rv.x); a1 = bf2f((unsigned short)(rv.x >> 16));
        a2 = bf2f((unsigned short)rv.y); a3 = bf2f((unsigned short)(rv.y >> 16));
        a4 = bf2f((unsigned short)rv.z); a5 = bf2f((unsigned short)(rv.z >> 16));
        a6 = bf2f((unsigned short)rv.w); a7 = bf2f((unsigned short)(rv.w >> 16));
    )
    if (s == 0 && valid) {
        float di = dis[i];
        float4 b4a = *reinterpret_cast<const float4*>(bias + 8 * ol);
        float4 b4b = *reinterpret_cast<const float4*>(bias + 8 * ol + 4);
        uint4 o;
        o.x = (unsigned)f2bf(fmaxf(fmaf(di, a0, b4a.x), 0.f))
            | ((unsigned)f2bf(fmaxf(fmaf(di, a1, b4a.y), 0.f)) << 16);
        o.y = (unsigned)f2bf(fmaxf(fmaf(di, a2, b4a.z), 0.f))
            | ((unsigned)f2bf(fmaxf(fmaf(di, a3, b4a.w), 0.f)) << 16);
        o.z = (unsigned)f2bf(fmaxf(fmaf(di, a4, b4b.x), 0.f))
            | ((unsigned)f2bf(fmaxf(fmaf(di, a5, b4b.y), 0.f)) << 16);
        o.w = (unsigned)f2bf(fmaxf(fmaf(di, a6, b4b.z), 0.f))
            | ((unsigned)f2bf(fmaxf(fmaf(di, a7, b4b.w), 0.f)) << 16);
        *reinterpret_cast<uint4*>(&hh[wv * 4 + p][8 * ol]) = o;
    }
    __syncthreads();

    const int m = lane & 15, q = lane >> 4;
    short8 af0 = *reinterpret_cast<const short8*>(&hh[m][q * 8]);        // kc=0
    short8 af1 = *reinterpret_cast<const short8*>(&hh[m][32 + q * 8]);   // kc=1
    short8 bf0 = *reinterpret_cast<const short8*>(&wf[(((wv << 1) | 0) * 64 + lane) * 8]);
    short8 bf1 = *reinterpret_cast<const short8*>(&wf[(((wv << 1) | 1) * 64 + lane) * 8]);
    f32x4 acc = {0, 0, 0, 0};
    acc = __builtin_amdgcn_mfma_f32_16x16x32_bf16(af0, bf0, acc, 0, 0, 0);
    acc = __builtin_amdgcn_mfma_f32_16x16x32_bf16(af1, bf1, acc, 0, 0, 0);
    #pragma unroll
    for (int reg = 0; reg < 4; ++reg) {
        int node = q * 4 + reg;
        int row = base16 + node;
        if (row < N)
            A2[(long)row * FEAT + wv * 16 + m] = f2bf(acc[reg] * dl[node]);
    }
}

// agg2 + scatter: LDS-stage the 4 rows, then ONE full-wave 64-lane contiguous
// atomicAdd per node (256B/instr -> TCC merges to full-line RMW).
__global__ __launch_bounds__(256) void k_agg2s(const unsigned short* __restrict__ A,
                                               const int* __restrict__ rp,
                                               const int* __restrict__ col,
                                               const float* __restrict__ dis,
                                               const float* __restrict__ bias,
                                               const int* __restrict__ uidx,
                                               const float* __restrict__ cntf,
                                               float* __restrict__ S, int N) {
    __shared__ float sbuf[4][4][65];
    AGG_BODY(
        uint4 rv = *reinterpret_cast<const uint4*>(A + (long)i * FEAT + 8 * ol);
        a0 = bf2f((unsigned short)rv.x); a1 = bf2f((unsigned short)(rv.x >> 16));
        a2 = bf2f((unsigned short)rv.y); a3 = bf2f((unsigned short)(rv.y >> 16));
        a4 = bf2f((unsigned short)rv.z); a5 = bf2f((unsigned short)(rv.z >> 16));
        a6 = bf2f((unsigned short)rv.w); a7 = bf2f((unsigned short)(rv.w >> 16));
    )
    if (s == 0) {
        float* dl = &sbuf[wv][p][8 * ol];
        dl[0] = a0; dl[1] = a1; dl[2] = a2; dl[3] = a3;
        dl[4] = a4; dl[5] = a5; dl[6] = a6; dl[7] = a7;
    }
    __syncthreads();
    const int base4 = blockIdx.x * 16 + wv * 4;
    const float bl = bias[lane];
    #pragma unroll
    for (int pp = 0; pp < 4; ++pp) {
        int node = base4 + pp;
        if (node < N) {
            int u = uidx[node];
            if ((unsigned)u < (unsigned)N) {
                float c = cntf[u];
                float wgt = (c > 0.f) ? (1.0f / c) : 0.f;
                float di = dis[node];
                float v = sbuf[wv][pp][lane];
                atomicAdd(&S[(long)u * FEAT + lane], wgt * fmaf(di, v, bl));
            }
        }
    }
}

extern "C" void kernel_launch(void* const* d_in, const int* in_sizes, int n_in,
                              void* d_out, int out_size, void* d_ws, size_t ws_size,
                              hipStream_t stream) {
    const float* x   = (const float*)d_in[0];
    const int* edge  = (const int*)d_in[1];
    const int* uidx  = (const int*)d_in[2];
    const float* W1  = (const float*)d_in[3];
    const float* b1  = (const float*)d_in[4];
    const float* W2  = (const float*)d_in[5];
    const float* b2  = (const float*)d_in[6];
    float* out       = (float*)d_out;

    const int N = in_sizes[2];       // 100000
    const int E = in_sizes[1] / 2;   // 1600000
    const int* src = edge;
    const int* dst = edge + E;

    const size_t fbuf = (size_t)N * FEAT * sizeof(float);
    const size_t abuf = (size_t)(N + 1) * FEAT * sizeof(unsigned short); // +zero row
    const int gE   = (E + 255) / 256;
    const int gN   = (N + 255) / 256;
    const int gN16 = (N + 15) / 16;
    const int gG   = (N + 63) / 64;
    const int gBH  = (E + BH_TILE - 1) / BH_TILE;
    const int nbScan = (N + SCAN_CHUNK - 1) / SCAN_CHUNK;
    const int KB = (N + BIN_R - 1) >> BIN_SHIFT;            // 196

    auto align256 = [](size_t v) { return (v + 255) & ~(size_t)255; };

    char* w = (char*)d_ws;
    size_t o = 0;
    float* dis  = (float*)(w + o); o = align256(o + (size_t)N * 4);
    float* cntf = (float*)(w + o); o = align256(o + (size_t)N * 4);
    int*   cntE = (int*)  (w + o); o = align256(o + (size_t)N * 4);   // gbc alias; adjacent to cntf
    int*   rp   = (int*)  (w + o); o = align256(o + (size_t)(N + 1) * 4);
    int*   ptot = (int*)  (w + o); o = align256(o + (size_t)1024 * 4); // bb aliases
    int*   poff = (int*)  (w + o); o = align256(o + (size_t)1024 * 4); // bcur aliases
    int*   col  = (int*)  (w + o); o = align256(o + (size_t)E * 4);
    size_t apsz = (size_t)E * 4 > abuf ? (size_t)E * 4 : abuf;
    char*  Ap   = w + o;           o = align256(o + apsz);            // pairs -> A2 (tier1) / A (tier2)
    const size_t need_base = o;
    unsigned short* Asep = (unsigned short*)(w + o); o = align256(o + abuf);
    const size_t need_fused = o;

    int* gbc  = cntE;
    int* bb   = ptot;
    int* bcur = poff;
    unsigned* pairs = (unsigned*)Ap;
    unsigned short* A2t1 = (unsigned short*)Ap;  // tier1: A2 over dead pairs
    unsigned short* At2  = (unsigned short*)Ap;  // tier2: A over dead pairs
    unsigned short* Hb = (unsigned short*)out;   // tier2: bf16 H in out

    const bool binOK = (KB <= 256) && (N <= (1 << (32 - BIN_SHIFT - 1)));
    const long NF4 = (long)N * FEAT / 4;

    if (ws_size >= need_fused && binOK) {
        // zero cntf (N floats) + gbc (KB ints) in one shot (adjacent regions)
        size_t zspan = (size_t)((char*)gbc - (char*)cntf) + (size_t)KB * 4;
        hipMemsetAsync(cntf, 0, zspan, stream);
        k_bhist<<<gBH, 256, 0, stream>>>(dst, gbc, uidx, cntf, (uint4*)out, NF4, E, N, KB);
        k_bscan<<<1, 256, 0, stream>>>(gbc, bb, bcur, rp + N, KB);
        k_binA  <<<(E + BIN_TILE - 1) / BIN_TILE, 256, 0, stream>>>(src, dst, bcur, pairs, E, N, KB);
        k_binB2g<<<KB, 1024, 0, stream>>>(pairs, bb, rp, col, dis, x, W1, Asep, N);
        k_agg1f <<<gN16, 256, 0, stream>>>(Asep, rp, col, dis, b1, W2, A2t1, N);
        k_agg2s <<<gN16, 256, 0, stream>>>(A2t1, rp, col, dis, b2, uidx, cntf, out, N);
    } else if (ws_size >= need_base && binOK) {
        size_t zspan = (size_t)((char*)gbc - (char*)cntf) + (size_t)KB * 4;
        hipMemsetAsync(cntf, 0, zspan, stream);
        k_bhist<<<gBH, 256, 0, stream>>>(dst, gbc, uidx, cntf, (uint4*)nullptr, 0, E, N, KB);
        k_bscan<<<1, 256, 0, stream>>>(gbc, bb, bcur, rp + N, KB);
        k_binA <<<(E + BIN_TILE - 1) / BIN_TILE, 256, 0, stream>>>(src, dst, bcur, pairs, E, N, KB);
        k_binB2<<<KB, 1024, 0, stream>>>(pairs, bb, rp, col, dis, N);

        k_gemm1<<<gG, 256, 0, stream>>>(x, W1, dis, At2, N);
        k_agg1 <<<gN16, 256, 0, stream>>>(At2, rp, col, dis, b1, Hb, N);
        k_gemm2<<<gG, 256, 0, stream>>>(Hb, W2, dis, At2, N);
        hipMemsetAsync(out, 0, fbuf, stream);
        k_agg2s<<<gN16, 256, 0, stream>>>(At2, rp, col, dis, b2, uidx, cntf, out, N);
    } else {
        hipMemsetAsync(cntE, 0, (size_t)N * 4, stream);
        k_hist <<<gE, 256, 0, stream>>>(dst, cntE, E, N);
        k_dis  <<<gN, 256, 0, stream>>>(cntE, dis, N);
        k_scan1<<<nbScan, SCAN_BS, 0, stream>>>(cntE, rp, ptot, N);
        k_scan2<<<1, 1024, 0, stream>>>(ptot, poff, rp + N, nbScan);
        k_scan3<<<nbScan, SCAN_BS, 0, stream>>>(rp, poff, N);
        hipMemsetAsync(cntE, 0, (size_t)N * 4, stream);
        k_fill <<<gE, 256, 0, stream>>>(src, dst, rp, cntE, col, E, N);
        hipMemsetAsync(cntf, 0, (size_t)N * 4, stream);
        k_ucnt <<<gN, 256, 0, stream>>>(uidx, cntf, N);
        k_gemm1<<<gG, 256, 0, stream>>>(x, W1, dis, At2, N);
        k_agg1 <<<gN16, 256, 0, stream>>>(At2, rp, col, dis, b1, Hb, N);
        k_gemm2<<<gG, 256, 0, stream>>>(Hb, W2, dis, At2, N);
        hipMemsetAsync(out, 0, fbuf, stream);
        k_agg2s<<<gN16, 256, 0, stream>>>(At2, rp, col, dis, b2, uidx, cntf, out, N);
    }
}

// Round 8
// 252.361 us; speedup vs baseline: 1.2991x; 1.0181x over previous
//
#include <hip/hip_runtime.h>
#include <hip/hip_bf16.h>

// GCN: h1 = relu(GCNConv(x, W1, b1)); out = scatter_mean(GCNConv(h1, W2, b2), user_idx)
// N=100000, E=1600000, dims 128 -> 64 -> 64. fp32 I/O, int32 indices.
//
// R19 profile: agg1f 43.6us (VALU 61%, 2.6M LDS bank conflicts) vs agg2s 42.6
// (VALU 36%, 0 conflicts): agg1f's 6250 blocks EACH re-stage W2 (16KB global
// read + 4096 scalar ds_write_u16 + 4096 f2bf). R20: precompute the W2
// fragment table ONCE in k_bscan (1-block kernel, spare capacity) into 8KB of
// workspace; agg1f threads load their 2 short8 fragments from global (L2-hot).
// Bit-identical (same f2bf, same index map). aggs otherwise at the verified
// random-gather fabric floor (FETCH ~86MB = cross-XCD duplication of A).

#define FEAT 64
#define INDIM 128

#define SCAN_BS 256
#define SCAN_ELEMS 8
#define SCAN_CHUNK (SCAN_BS * SCAN_ELEMS)

#define BIN_SHIFT 9
#define BIN_R 512
#define BIN_TILE 2048
#define BH_TILE 2048

typedef __attribute__((ext_vector_type(8))) short short8;
typedef __attribute__((ext_vector_type(4))) float f32x4;

__device__ __forceinline__ unsigned short f2bf(float f) {
    unsigned u = __float_as_uint(f);
    unsigned r = u + 0x7FFFu + ((u >> 16) & 1u);
    return (unsigned short)(r >> 16);
}
__device__ __forceinline__ float bf2f(unsigned short v) {
    return __uint_as_float(((unsigned)v) << 16);
}

// ==================== bucket-level CSR build ====================

// histogram + ucnt + optional out-zeroing (NO fences -- see R18 post-mortem)
__global__ __launch_bounds__(256) void k_bhist(const int* __restrict__ dst,
                                               int* __restrict__ gbc,
                                               const int* __restrict__ uidx,
                                               float* __restrict__ cntf,
                                               uint4* __restrict__ outz, long nz4,
                                               int E, int N, int KB) {
    __shared__ int h[256];
    const int tid = threadIdx.x;
    h[tid] = 0;
    __syncthreads();
    const int base = blockIdx.x * BH_TILE;
    #pragma unroll
    for (int t = 0; t < BH_TILE / 256; ++t) {
        int e = base + t * 256 + tid;
        if (e < E) {
            int d = dst[e];
            if ((unsigned)d < (unsigned)N) atomicAdd(&h[d >> BIN_SHIFT], 1);
        }
    }
    int i = blockIdx.x * 256 + tid;
    if (i < N) {
        int u = uidx[i];
        if ((unsigned)u < (unsigned)N) atomicAdd(&cntf[u], 1.0f);
    }
    if (outz) {
        uint4 z; z.x = 0; z.y = 0; z.z = 0; z.w = 0;
        const long stride = (long)gridDim.x * 256;
        for (long idx = (long)blockIdx.x * 256 + tid; idx < nz4; idx += stride)
            outz[idx] = z;
    }
    __syncthreads();
    if (tid < KB && h[tid]) atomicAdd(&gbc[tid], h[tid]);
}

// bucket scan + (optional) one-time W2 fragment-table precompute
__global__ __launch_bounds__(256) void k_bscan(const int* __restrict__ gbc,
                                               int* __restrict__ bb,
                                               int* __restrict__ bcur,
                                               int* __restrict__ rpN, int KB,
                                               const float* __restrict__ W2,
                                               unsigned short* __restrict__ wfrag) {
    __shared__ int lds[256];
    const int tid = threadIdx.x;
    if (wfrag) {
        for (int ii = tid; ii < FEAT * FEAT; ii += 256) {
            int k = ii >> 6, n = ii & 63;
            int ct = n >> 4, kc = k >> 5, r = k & 31;
            int owner = ((r >> 3) << 4) | (n & 15);
            wfrag[(((ct << 1) | kc) * 64 + owner) * 8 + (r & 7)] = f2bf(W2[ii]);
        }
    }
    int v = (tid < KB) ? gbc[tid] : 0;
    lds[tid] = v;
    __syncthreads();
    for (int d = 1; d < 256; d <<= 1) {
        int t = (tid >= d) ? lds[tid - d] : 0;
        __syncthreads();
        lds[tid] += t;
        __syncthreads();
    }
    int excl = lds[tid] - v;
    if (tid < KB) { bb[tid] = excl; bcur[tid] = excl; }
    if (tid == 255) { bb[KB] = lds[255]; *rpN = lds[255]; }
}

// tile-reorder edges by bucket; packed (src<<BIN_SHIFT)|local_dst
__global__ __launch_bounds__(256) void k_binA(const int* __restrict__ src,
                                              const int* __restrict__ dst,
                                              int* __restrict__ bcur,
                                              unsigned* __restrict__ pairs,
                                              int E, int N, int KB) {
    __shared__ unsigned lbuf[BIN_TILE];          // 8 KB
    __shared__ unsigned short bkt[BIN_TILE];     // 4 KB
    __shared__ int lcnt[256];
    __shared__ int loff[256];
    __shared__ int lbase[256];
    __shared__ int tot;
    const int tid = threadIdx.x;
    const int base = blockIdx.x * BIN_TILE;

    lcnt[tid] = 0;
    __syncthreads();

    int mys[BIN_TILE / 256], myd[BIN_TILE / 256], myb[BIN_TILE / 256];
    #pragma unroll
    for (int t = 0; t < BIN_TILE / 256; ++t) {
        int e = base + t * 256 + tid;
        int s = 0, d = -1;
        if (e < E) { s = src[e]; d = dst[e]; }
        if ((unsigned)d >= (unsigned)N) d = -1;
        if ((unsigned)s >= (unsigned)N) s = 0;
        mys[t] = s; myd[t] = d;
        myb[t] = (d >= 0) ? (d >> BIN_SHIFT) : -1;
        if (myb[t] >= 0) atomicAdd(&lcnt[myb[t]], 1);
    }
    __syncthreads();

    int v = lcnt[tid];
    loff[tid] = v;
    __syncthreads();
    for (int d = 1; d < 256; d <<= 1) {
        int t2 = (tid >= d) ? loff[tid - d] : 0;
        __syncthreads();
        loff[tid] += t2;
        __syncthreads();
    }
    if (tid == 255) tot = loff[255];
    int excl = loff[tid] - v;
    __syncthreads();
    loff[tid] = excl;
    lcnt[tid] = excl;
    if (tid < KB && v > 0) lbase[tid] = atomicAdd(&bcur[tid], v);
    __syncthreads();

    #pragma unroll
    for (int t = 0; t < BIN_TILE / 256; ++t) {
        if (myb[t] >= 0) {
            int pos = atomicAdd(&lcnt[myb[t]], 1);
            lbuf[pos] = ((unsigned)mys[t] << BIN_SHIFT) | (unsigned)(myd[t] & (BIN_R - 1));
            bkt[pos] = (unsigned short)myb[t];
        }
    }
    __syncthreads();

    const int T = tot;
    for (int i = tid; i < T; i += 256) {
        int b = bkt[i];
        pairs[lbase[b] + (i - loff[b])] = lbuf[i];
    }
}

// FUSED binB2+gemm1: one WG (16 waves) per bucket of 512 nodes.
__global__ __launch_bounds__(1024) void k_binB2g(const unsigned* __restrict__ pairs,
                                                 const int* __restrict__ bb,
                                                 int* __restrict__ rp,
                                                 int* __restrict__ col,
                                                 float* __restrict__ dis,
                                                 const float* __restrict__ x,
                                                 const float* __restrict__ W1,
                                                 unsigned short* __restrict__ A, int N) {
    __shared__ int cnt[BIN_R];
    __shared__ int cur[BIN_R];
    __shared__ int ssum[256];
    __shared__ short wf[4 * 4 * 64 * 8];   // W1 fragments, 16 KB
    const int tid = threadIdx.x;
    const int b = blockIdx.x;
    const int n0 = b << BIN_SHIFT;
    const int n1 = min(n0 + BIN_R, N);
    const int nn = n1 - n0;
    const int e0 = bb[b];
    const int e1 = bb[b + 1];

    for (int ii = tid; ii < INDIM * FEAT; ii += 1024) {
        int k = ii >> 6, n = ii & 63;
        int ct = n >> 4, kc = k >> 5, r = k & 31;
        int owner = ((r >> 3) << 4) | (n & 15);
        wf[(((ct << 2) | kc) * 64 + owner) * 8 + (r & 7)] = (short)f2bf(W1[ii]);
    }
    if (b == 0 && tid >= 512 && tid < 520) {      // zero row N of A
        uint4 z; z.x = 0; z.y = 0; z.z = 0; z.w = 0;
        *reinterpret_cast<uint4*>(A + (long)N * FEAT + (tid - 512) * 8) = z;
    }

    for (int i = tid; i < nn; i += 1024) cnt[i] = 0;
    __syncthreads();
    for (int i = e0 + tid; i < e1; i += 1024) {
        atomicAdd(&cnt[pairs[i] & (BIN_R - 1)], 1);
    }
    __syncthreads();

    const int i0 = 2 * tid;
    int c0 = 0, c1 = 0;
    if (tid < 256) {
        c0 = (i0     < nn) ? cnt[i0]     : 0;
        c1 = (i0 + 1 < nn) ? cnt[i0 + 1] : 0;
        ssum[tid] = c0 + c1;
    }
    __syncthreads();
    for (int d = 1; d < 256; d <<= 1) {
        int t = 0;
        if (tid < 256 && tid >= d) t = ssum[tid - d];
        __syncthreads();
        if (tid < 256) ssum[tid] += t;
        __syncthreads();
    }
    if (tid < 256) {
        int excl = ssum[tid] - (c0 + c1);
        if (i0 < nn) {
            cur[i0] = e0 + excl;
            rp[n0 + i0] = e0 + excl;
            dis[n0 + i0] = rsqrtf((float)c0 + 1.0f);
        }
        if (i0 + 1 < nn) {
            cur[i0 + 1] = e0 + excl + c0;
            rp[n0 + i0 + 1] = e0 + excl + c0;
            dis[n0 + i0 + 1] = rsqrtf((float)c1 + 1.0f);
        }
    }
    __syncthreads();

    for (int i = e0 + tid; i < e1; i += 1024) {
        unsigned p = pairs[i];
        int pos = atomicAdd(&cur[p & (BIN_R - 1)], 1);
        col[pos] = (int)(p >> BIN_SHIFT);
    }
    __syncthreads();

    // ---- gemm1 phase: 16 waves x 32 rows, MFMA 16x16x32 bf16 ----
    const int lane = tid & 63;
    const int w = tid >> 6;
    const int m = lane & 15, q = lane >> 4;
    #pragma unroll
    for (int t = 0; t < 2; ++t) {
        int lrow = w * 32 + t * 16 + m;
        int gr = n0 + lrow;
        int rl = gr < N ? gr : (N - 1);
        const float* xp = x + (long)rl * INDIM + q * 8;
        f32x4 acc[4] = {{0,0,0,0},{0,0,0,0},{0,0,0,0},{0,0,0,0}};
        #pragma unroll
        for (int kc = 0; kc < 4; ++kc) {
            float4 v0 = *reinterpret_cast<const float4*>(xp + kc * 32);
            float4 v1 = *reinterpret_cast<const float4*>(xp + kc * 32 + 4);
            short8 a;
            a[0]=(short)f2bf(v0.x); a[1]=(short)f2bf(v0.y); a[2]=(short)f2bf(v0.z); a[3]=(short)f2bf(v0.w);
            a[4]=(short)f2bf(v1.x); a[5]=(short)f2bf(v1.y); a[6]=(short)f2bf(v1.z); a[7]=(short)f2bf(v1.w);
            #pragma unroll
            for (int ct = 0; ct < 4; ++ct) {
                short8 bf = *reinterpret_cast<const short8*>(&wf[(((ct << 2) | kc) * 64 + lane) * 8]);
                acc[ct] = __builtin_amdgcn_mfma_f32_16x16x32_bf16(a, bf, acc[ct], 0, 0, 0);
            }
        }
        #pragma unroll
        for (int reg = 0; reg < 4; ++reg) {
            int ld = w * 32 + t * 16 + q * 4 + reg;
            if (ld < nn) {
                float sc = rsqrtf((float)cnt[ld] + 1.0f);
                int row = n0 + ld;
                #pragma unroll
                for (int ct = 0; ct < 4; ++ct)
                    A[(long)row * FEAT + ct * 16 + m] = f2bf(acc[ct][reg] * sc);
            }
        }
    }
}

// plain binB2 (fallback tiers)
__global__ __launch_bounds__(1024) void k_binB2(const unsigned* __restrict__ pairs,
                                                const int* __restrict__ bb,
                                                int* __restrict__ rp,
                                                int* __restrict__ col,
                                                float* __restrict__ dis, int N) {
    __shared__ int cnt[BIN_R];
    __shared__ int cur[BIN_R];
    __shared__ int ssum[256];
    const int tid = threadIdx.x;
    const int b = blockIdx.x;
    const int n0 = b << BIN_SHIFT;
    const int n1 = min(n0 + BIN_R, N);
    const int nn = n1 - n0;
    const int e0 = bb[b];
    const int e1 = bb[b + 1];

    for (int i = tid; i < nn; i += 1024) cnt[i] = 0;
    __syncthreads();
    for (int i = e0 + tid; i < e1; i += 1024) {
        atomicAdd(&cnt[pairs[i] & (BIN_R - 1)], 1);
    }
    __syncthreads();

    const int i0 = 2 * tid;
    int c0 = 0, c1 = 0;
    if (tid < 256) {
        c0 = (i0     < nn) ? cnt[i0]     : 0;
        c1 = (i0 + 1 < nn) ? cnt[i0 + 1] : 0;
        ssum[tid] = c0 + c1;
    }
    __syncthreads();
    for (int d = 1; d < 256; d <<= 1) {
        int t = 0;
        if (tid < 256 && tid >= d) t = ssum[tid - d];
        __syncthreads();
        if (tid < 256) ssum[tid] += t;
        __syncthreads();
    }
    if (tid < 256) {
        int excl = ssum[tid] - (c0 + c1);
        if (i0 < nn) {
            cur[i0] = e0 + excl;
            rp[n0 + i0] = e0 + excl;
            dis[n0 + i0] = rsqrtf((float)c0 + 1.0f);
        }
        if (i0 + 1 < nn) {
            cur[i0 + 1] = e0 + excl + c0;
            rp[n0 + i0 + 1] = e0 + excl + c0;
            dis[n0 + i0 + 1] = rsqrtf((float)c1 + 1.0f);
        }
    }
    __syncthreads();

    for (int i = e0 + tid; i < e1; i += 1024) {
        unsigned p = pairs[i];
        int pos = atomicAdd(&cur[p & (BIN_R - 1)], 1);
        col[pos] = (int)(p >> BIN_SHIFT);
    }
}

// ==================== fallback CSR build (proven path) ====================

__global__ __launch_bounds__(256) void k_hist(const int* __restrict__ dst,
                                              int* __restrict__ cntE, int E, int N) {
    int e = blockIdx.x * 256 + threadIdx.x;
    if (e < E) {
        int d = dst[e];
        if ((unsigned)d < (unsigned)N) atomicAdd(&cntE[d], 1);
    }
}
__global__ __launch_bounds__(256) void k_dis(const int* __restrict__ cntE,
                                             float* __restrict__ dis, int N) {
    int i = blockIdx.x * 256 + threadIdx.x;
    if (i < N) dis[i] = rsqrtf((float)cntE[i] + 1.0f);
}
__global__ __launch_bounds__(SCAN_BS) void k_scan1(const int* __restrict__ c,
                                                   int* __restrict__ rp,
                                                   int* __restrict__ ptot, int N) {
    __shared__ int lds[SCAN_BS];
    const int base = blockIdx.x * SCAN_CHUNK;
    const int tb = base + threadIdx.x * SCAN_ELEMS;
    int vals[SCAN_ELEMS];
    int s = 0;
    #pragma unroll
    for (int k = 0; k < SCAN_ELEMS; ++k) {
        int idx = tb + k;
        int v = (idx < N) ? c[idx] : 0;
        vals[k] = s;
        s += v;
    }
    lds[threadIdx.x] = s;
    __syncthreads();
    for (int d = 1; d < SCAN_BS; d <<= 1) {
        int v = (threadIdx.x >= d) ? lds[threadIdx.x - d] : 0;
        __syncthreads();
        lds[threadIdx.x] += v;
        __syncthreads();
    }
    int toff = (threadIdx.x == 0) ? 0 : lds[threadIdx.x - 1];
    #pragma unroll
    for (int k = 0; k < SCAN_ELEMS; ++k) {
        int idx = tb + k;
        if (idx < N) rp[idx] = toff + vals[k];
    }
    if (threadIdx.x == SCAN_BS - 1) ptot[blockIdx.x] = lds[SCAN_BS - 1];
}
__global__ __launch_bounds__(1024) void k_scan2(int* __restrict__ ptot,
                                                int* __restrict__ poff,
                                                int* __restrict__ rpN, int nb) {
    __shared__ int lds[1024];
    int tid = threadIdx.x;
    lds[tid] = (tid < nb) ? ptot[tid] : 0;
    __syncthreads();
    for (int d = 1; d < 1024; d <<= 1) {
        int v = (tid >= d) ? lds[tid - d] : 0;
        __syncthreads();
        lds[tid] += v;
        __syncthreads();
    }
    if (tid < nb) poff[tid] = (tid == 0) ? 0 : lds[tid - 1];
    if (tid == nb - 1) *rpN = lds[tid];
}
__global__ __launch_bounds__(SCAN_BS) void k_scan3(int* __restrict__ rp,
                                                   const int* __restrict__ poff, int N) {
    int off = poff[blockIdx.x];
    const int tb = blockIdx.x * SCAN_CHUNK + threadIdx.x * SCAN_ELEMS;
    #pragma unroll
    for (int k = 0; k < SCAN_ELEMS; ++k) {
        int idx = tb + k;
        if (idx < N) rp[idx] += off;
    }
}
__global__ __launch_bounds__(256) void k_fill(const int* __restrict__ src,
                                              const int* __restrict__ dst,
                                              const int* __restrict__ rp,
                                              int* __restrict__ tmp,
                                              int* __restrict__ col, int E, int N) {
    int e = blockIdx.x * 256 + threadIdx.x;
    if (e >= E) return;
    int s = src[e], d = dst[e];
    if ((unsigned)s >= (unsigned)N) s = 0;
    if ((unsigned)d >= (unsigned)N) return;
    int r = atomicAdd(&tmp[d], 1);
    col[rp[d] + r] = s;
}

__global__ __launch_bounds__(256) void k_ucnt(const int* __restrict__ uidx,
                                              float* __restrict__ cntf, int N) {
    int i = blockIdx.x * 256 + threadIdx.x;
    if (i < N) {
        int u = uidx[i];
        if ((unsigned)u < (unsigned)N) atomicAdd(&cntf[u], 1.0f);
    }
}

// ==================== MFMA GEMMs (fallback tiers) ====================

__global__ __launch_bounds__(256) void k_gemm1(const float* __restrict__ x,
                                               const float* __restrict__ W,
                                               const float* __restrict__ scale,
                                               unsigned short* __restrict__ out, int N) {
    __shared__ short wf[4 * 4 * 64 * 8];
    const int tid = threadIdx.x;
    if (blockIdx.x == 0 && tid < 8) {
        uint4 z; z.x = 0; z.y = 0; z.z = 0; z.w = 0;
        *reinterpret_cast<uint4*>(out + (long)N * FEAT + tid * 8) = z;
    }
    for (int i = tid; i < INDIM * FEAT; i += 256) {
        int k = i >> 6, n = i & 63;
        int ct = n >> 4, kc = k >> 5, r = k & 31;
        int owner = ((r >> 3) << 4) | (n & 15);
        wf[(((ct << 2) | kc) * 64 + owner) * 8 + (r & 7)] = (short)f2bf(W[i]);
    }
    __syncthreads();

    const int lane = tid & 63;
    const int m = lane & 15, q = lane >> 4;
    const int row0 = blockIdx.x * 64 + (tid >> 6) * 16;

    short8 bfr[4][4];
    #pragma unroll
    for (int ct = 0; ct < 4; ++ct)
        #pragma unroll
        for (int kc = 0; kc < 4; ++kc)
            bfr[ct][kc] = *reinterpret_cast<const short8*>(&wf[(((ct << 2) | kc) * 64 + lane) * 8]);

    int gr = row0 + m;
    int rl = gr < N ? gr : (N - 1);
    const float* xp = x + (long)rl * INDIM + q * 8;

    f32x4 acc[4] = {{0,0,0,0},{0,0,0,0},{0,0,0,0},{0,0,0,0}};
    #pragma unroll
    for (int kc = 0; kc < 4; ++kc) {
        float4 v0 = *reinterpret_cast<const float4*>(xp + kc * 32);
        float4 v1 = *reinterpret_cast<const float4*>(xp + kc * 32 + 4);
        short8 a;
        a[0]=(short)f2bf(v0.x); a[1]=(short)f2bf(v0.y); a[2]=(short)f2bf(v0.z); a[3]=(short)f2bf(v0.w);
        a[4]=(short)f2bf(v1.x); a[5]=(short)f2bf(v1.y); a[6]=(short)f2bf(v1.z); a[7]=(short)f2bf(v1.w);
        #pragma unroll
        for (int ct = 0; ct < 4; ++ct)
            acc[ct] = __builtin_amdgcn_mfma_f32_16x16x32_bf16(a, bfr[ct][kc], acc[ct], 0, 0, 0);
    }

    #pragma unroll
    for (int reg = 0; reg < 4; ++reg) {
        int row = row0 + q * 4 + reg;
        if (row < N) {
            float sc = scale[row];
            #pragma unroll
            for (int ct = 0; ct < 4; ++ct)
                out[(long)row * FEAT + ct * 16 + m] = f2bf(acc[ct][reg] * sc);
        }
    }
}

__global__ __launch_bounds__(256) void k_gemm2(const unsigned short* __restrict__ h,
                                               const float* __restrict__ W,
                                               const float* __restrict__ scale,
                                               unsigned short* __restrict__ out, int N) {
    __shared__ short wf[4 * 2 * 64 * 8];
    const int tid = threadIdx.x;
    if (blockIdx.x == 0 && tid < 8) {
        uint4 z; z.x = 0; z.y = 0; z.z = 0; z.w = 0;
        *reinterpret_cast<uint4*>(out + (long)N * FEAT + tid * 8) = z;
    }
    for (int i = tid; i < FEAT * FEAT; i += 256) {
        int k = i >> 6, n = i & 63;
        int ct = n >> 4, kc = k >> 5, r = k & 31;
        int owner = ((r >> 3) << 4) | (n & 15);
        wf[(((ct << 1) | kc) * 64 + owner) * 8 + (r & 7)] = (short)f2bf(W[i]);
    }
    __syncthreads();

    const int lane = tid & 63;
    const int m = lane & 15, q = lane >> 4;
    const int row0 = blockIdx.x * 64 + (tid >> 6) * 16;

    short8 bfr[4][2];
    #pragma unroll
    for (int ct = 0; ct < 4; ++ct)
        #pragma unroll
        for (int kc = 0; kc < 2; ++kc)
            bfr[ct][kc] = *reinterpret_cast<const short8*>(&wf[(((ct << 1) | kc) * 64 + lane) * 8]);

    int gr = row0 + m;
    int rl = gr < N ? gr : (N - 1);
    const unsigned short* hp = h + (long)rl * FEAT + q * 8;

    f32x4 acc[4] = {{0,0,0,0},{0,0,0,0},{0,0,0,0},{0,0,0,0}};
    #pragma unroll
    for (int kc = 0; kc < 2; ++kc) {
        short8 a = *reinterpret_cast<const short8*>(hp + kc * 32);
        #pragma unroll
        for (int ct = 0; ct < 4; ++ct)
            acc[ct] = __builtin_amdgcn_mfma_f32_16x16x32_bf16(a, bfr[ct][kc], acc[ct], 0, 0, 0);
    }

    #pragma unroll
    for (int reg = 0; reg < 4; ++reg) {
        int row = row0 + q * 4 + reg;
        if (row < N) {
            float sc = scale[row];
            #pragma unroll
            for (int ct = 0; ct < 4; ++ct)
                out[(long)row * FEAT + ct * 16 + m] = f2bf(acc[ct][reg] * sc);
        }
    }
}

// ==================== pull aggregation: 4 nodes/wave, 8 gathers in flight =====
// lane = 16*p + 8*s + ol (p = node 0..3, s = slot-parity 0..1, ol = octet).
// Each iteration covers 16 edges/node; 8 independent uint4 gathers in flight.
// Dummy slots read zero row N of A (L1-hot, adds 0). Reduce: one shfl_xor(8).

#define ACC8(r)                                                                  \
    a0 += bf2f((unsigned short)(r).x);                                           \
    a1 += bf2f((unsigned short)((r).x >> 16));                                   \
    a2 += bf2f((unsigned short)(r).y);                                           \
    a3 += bf2f((unsigned short)((r).y >> 16));                                   \
    a4 += bf2f((unsigned short)(r).z);                                           \
    a5 += bf2f((unsigned short)((r).z >> 16));                                   \
    a6 += bf2f((unsigned short)(r).w);                                           \
    a7 += bf2f((unsigned short)((r).w >> 16));

#define AGG_BODY(SELF_INIT)                                                      \
    const int lane = threadIdx.x & 63;                                           \
    const int wv = threadIdx.x >> 6;                                             \
    const int p  = lane >> 4;                                                    \
    const int s  = (lane >> 3) & 1;                                              \
    const int ol = lane & 7;                                                     \
    const int i  = blockIdx.x * 16 + wv * 4 + p;                                 \
    const bool valid = (i < N);                                                  \
    const int jb = valid ? rp[i] : 0;                                            \
    const int je = valid ? rp[i + 1] : 0;                                        \
    float a0=0.f,a1=0.f,a2=0.f,a3=0.f,a4=0.f,a5=0.f,a6=0.f,a7=0.f;               \
    if (valid && s == 0) { SELF_INIT }                                           \
    for (int j0 = jb; j0 < je; j0 += 16) {                                       \
        int j1 = j0 + s;                                                         \
        int c1 = (j1      < je) ? col[j1]      : N;                              \
        int c2 = (j1 + 2  < je) ? col[j1 + 2]  : N;                              \
        int c3 = (j1 + 4  < je) ? col[j1 + 4]  : N;                              \
        int c4 = (j1 + 6  < je) ? col[j1 + 6]  : N;                              \
        int c5 = (j1 + 8  < je) ? col[j1 + 8]  : N;                              \
        int c6 = (j1 + 10 < je) ? col[j1 + 10] : N;                              \
        int c7 = (j1 + 12 < je) ? col[j1 + 12] : N;                              \
        int c8 = (j1 + 14 < je) ? col[j1 + 14] : N;                              \
        uint4 r1 = *reinterpret_cast<const uint4*>(A + (long)c1 * FEAT + 8 * ol);\
        uint4 r2 = *reinterpret_cast<const uint4*>(A + (long)c2 * FEAT + 8 * ol);\
        uint4 r3 = *reinterpret_cast<const uint4*>(A + (long)c3 * FEAT + 8 * ol);\
        uint4 r4 = *reinterpret_cast<const uint4*>(A + (long)c4 * FEAT + 8 * ol);\
        uint4 r5 = *reinterpret_cast<const uint4*>(A + (long)c5 * FEAT + 8 * ol);\
        uint4 r6 = *reinterpret_cast<const uint4*>(A + (long)c6 * FEAT + 8 * ol);\
        uint4 r7 = *reinterpret_cast<const uint4*>(A + (long)c7 * FEAT + 8 * ol);\
        uint4 r8 = *reinterpret_cast<const uint4*>(A + (long)c8 * FEAT + 8 * ol);\
        ACC8(r1)                                                                 \
        ACC8(r2)                                                                 \
        ACC8(r3)                                                                 \
        ACC8(r4)                                                                 \
        ACC8(r5)                                                                 \
        ACC8(r6)                                                                 \
        ACC8(r7)                                                                 \
        ACC8(r8)                                                                 \
    }                                                                            \
    a0 += __shfl_xor(a0, 8);  a1 += __shfl_xor(a1, 8);                           \
    a2 += __shfl_xor(a2, 8);  a3 += __shfl_xor(a3, 8);                           \
    a4 += __shfl_xor(a4, 8);  a5 += __shfl_xor(a5, 8);                           \
    a6 += __shfl_xor(a6, 8);  a7 += __shfl_xor(a7, 8);

// mid-tier fallback: agg1 writes relu(di*sum + b) as PACKED BF16 to Hb
__global__ __launch_bounds__(256) void k_agg1(const unsigned short* __restrict__ A,
                                              const int* __restrict__ rp,
                                              const int* __restrict__ col,
                                              const float* __restrict__ dis,
                                              const float* __restrict__ bias,
                                              unsigned short* __restrict__ H, int N) {
    AGG_BODY(
        uint4 rv = *reinterpret_cast<const uint4*>(A + (long)i * FEAT + 8 * ol);
        a0 = bf2f((unsigned short)rv.x); a1 = bf2f((unsigned short)(rv.x >> 16));
        a2 = bf2f((unsigned short)rv.y); a3 = bf2f((unsigned short)(rv.y >> 16));
        a4 = bf2f((unsigned short)rv.z); a5 = bf2f((unsigned short)(rv.z >> 16));
        a6 = bf2f((unsigned short)rv.w); a7 = bf2f((unsigned short)(rv.w >> 16));
    )
    if (s == 0 && valid) {
        float di = dis[i];
        float4 b4a = *reinterpret_cast<const float4*>(bias + 8 * ol);
        float4 b4b = *reinterpret_cast<const float4*>(bias + 8 * ol + 4);
        uint4 o;
        o.x = (unsigned)f2bf(fmaxf(fmaf(di, a0, b4a.x), 0.f))
            | ((unsigned)f2bf(fmaxf(fmaf(di, a1, b4a.y), 0.f)) << 16);
        o.y = (unsigned)f2bf(fmaxf(fmaf(di, a2, b4a.z), 0.f))
            | ((unsigned)f2bf(fmaxf(fmaf(di, a3, b4a.w), 0.f)) << 16);
        o.z = (unsigned)f2bf(fmaxf(fmaf(di, a4, b4b.x), 0.f))
            | ((unsigned)f2bf(fmaxf(fmaf(di, a5, b4b.y), 0.f)) << 16);
        o.w = (unsigned)f2bf(fmaxf(fmaf(di, a6, b4b.z), 0.f))
            | ((unsigned)f2bf(fmaxf(fmaf(di, a7, b4b.w), 0.f)) << 16);
        *reinterpret_cast<uint4*>(H + (long)i * FEAT + 8 * ol) = o;
    }
}

// FUSED agg1+gemm2: block = 16 nodes = one 16x64 MFMA tile.
// W2 fragments come pre-converted from global (wfrag, L2-hot) -- no LDS
// staging, no per-block conversion (R20).
__global__ __launch_bounds__(256) void k_agg1f(const unsigned short* __restrict__ A,
                                               const int* __restrict__ rp,
                                               const int* __restrict__ col,
                                               const float* __restrict__ dis,
                                               const float* __restrict__ bias,
                                               const unsigned short* __restrict__ wfrag,
                                               unsigned short* __restrict__ A2, int N) {
    __shared__ unsigned short hh[16][72];      // h1 bf16, padded rows
    __shared__ float dl[16];
    const int tid = threadIdx.x;
    const int base16 = blockIdx.x * 16;
    if (tid < 16) {
        int node = base16 + tid;
        dl[tid] = (node < N) ? dis[node] : 0.f;
    }
    if (blockIdx.x == 0 && tid >= 32 && tid < 40) {
        uint4 z; z.x = 0; z.y = 0; z.z = 0; z.w = 0;
        *reinterpret_cast<uint4*>(A2 + (long)N * FEAT + (tid - 32) * 8) = z;
    }

    AGG_BODY(
        uint4 rv = *reinterpret_cast<const uint4*>(A + (long)i * FEAT + 8 * ol);
        a0 = bf2f((unsigned short)rv.x); a1 = bf2f((unsigned short)(rv.x >> 16));
        a2 = bf2f((unsigned short)rv.y); a3 = bf2f((unsigned short)(rv.y >> 16));
        a4 = bf2f((unsigned short)rv.z); a5 = bf2f((unsigned short)(rv.z >> 16));
        a6 = bf2f((unsigned short)rv.w); a7 = bf2f((unsigned short)(rv.w >> 16));
    )
    if (s == 0 && valid) {
        float di = dis[i];
        float4 b4a = *reinterpret_cast<const float4*>(bias + 8 * ol);
        float4 b4b = *reinterpret_cast<const float4*>(bias + 8 * ol + 4);
        uint4 o;
        o.x = (unsigned)f2bf(fmaxf(fmaf(di, a0, b4a.x), 0.f))
            | ((unsigned)f2bf(fmaxf(fmaf(di, a1, b4a.y), 0.f)) << 16);
        o.y = (unsigned)f2bf(fmaxf(fmaf(di, a2, b4a.z), 0.f))
            | ((unsigned)f2bf(fmaxf(fmaf(di, a3, b4a.w), 0.f)) << 16);
        o.z = (unsigned)f2bf(fmaxf(fmaf(di, a4, b4b.x), 0.f))
            | ((unsigned)f2bf(fmaxf(fmaf(di, a5, b4b.y), 0.f)) << 16);
        o.w = (unsigned)f2bf(fmaxf(fmaf(di, a6, b4b.z), 0.f))
            | ((unsigned)f2bf(fmaxf(fmaf(di, a7, b4b.w), 0.f)) << 16);
        *reinterpret_cast<uint4*>(&hh[wv * 4 + p][8 * ol]) = o;
    }
    __syncthreads();

    const int m = lane & 15, q = lane >> 4;
    short8 af0 = *reinterpret_cast<const short8*>(&hh[m][q * 8]);        // kc=0
    short8 af1 = *reinterpret_cast<const short8*>(&hh[m][32 + q * 8]);   // kc=1
    short8 bf0 = *reinterpret_cast<const short8*>(wfrag + (((wv << 1) | 0) * 64 + lane) * 8);
    short8 bf1 = *reinterpret_cast<const short8*>(wfrag + (((wv << 1) | 1) * 64 + lane) * 8);
    f32x4 acc = {0, 0, 0, 0};
    acc = __builtin_amdgcn_mfma_f32_16x16x32_bf16(af0, bf0, acc, 0, 0, 0);
    acc = __builtin_amdgcn_mfma_f32_16x16x32_bf16(af1, bf1, acc, 0, 0, 0);
    #pragma unroll
    for (int reg = 0; reg < 4; ++reg) {
        int node = q * 4 + reg;
        int row = base16 + node;
        if (row < N)
            A2[(long)row * FEAT + wv * 16 + m] = f2bf(acc[reg] * dl[node]);
    }
}

// agg2 + scatter: LDS-stage the 4 rows, then ONE full-wave 64-lane contiguous
// atomicAdd per node (256B/instr -> TCC merges to full-line RMW).
__global__ __launch_bounds__(256) void k_agg2s(const unsigned short* __restrict__ A,
                                               const int* __restrict__ rp,
                                               const int* __restrict__ col,
                                               const float* __restrict__ dis,
                                               const float* __restrict__ bias,
                                               const int* __restrict__ uidx,
                                               const float* __restrict__ cntf,
                                               float* __restrict__ S, int N) {
    __shared__ float sbuf[4][4][65];
    AGG_BODY(
        uint4 rv = *reinterpret_cast<const uint4*>(A + (long)i * FEAT + 8 * ol);
        a0 = bf2f((unsigned short)rv.x); a1 = bf2f((unsigned short)(rv.x >> 16));
        a2 = bf2f((unsigned short)rv.y); a3 = bf2f((unsigned short)(rv.y >> 16));
        a4 = bf2f((unsigned short)rv.z); a5 = bf2f((unsigned short)(rv.z >> 16));
        a6 = bf2f((unsigned short)rv.w); a7 = bf2f((unsigned short)(rv.w >> 16));
    )
    if (s == 0) {
        float* dl = &sbuf[wv][p][8 * ol];
        dl[0] = a0; dl[1] = a1; dl[2] = a2; dl[3] = a3;
        dl[4] = a4; dl[5] = a5; dl[6] = a6; dl[7] = a7;
    }
    __syncthreads();
    const int base4 = blockIdx.x * 16 + wv * 4;
    const float bl = bias[lane];
    #pragma unroll
    for (int pp = 0; pp < 4; ++pp) {
        int node = base4 + pp;
        if (node < N) {
            int u = uidx[node];
            if ((unsigned)u < (unsigned)N) {
                float c = cntf[u];
                float wgt = (c > 0.f) ? (1.0f / c) : 0.f;
                float di = dis[node];
                float v = sbuf[wv][pp][lane];
                atomicAdd(&S[(long)u * FEAT + lane], wgt * fmaf(di, v, bl));
            }
        }
    }
}

extern "C" void kernel_launch(void* const* d_in, const int* in_sizes, int n_in,
                              void* d_out, int out_size, void* d_ws, size_t ws_size,
                              hipStream_t stream) {
    const float* x   = (const float*)d_in[0];
    const int* edge  = (const int*)d_in[1];
    const int* uidx  = (const int*)d_in[2];
    const float* W1  = (const float*)d_in[3];
    const float* b1  = (const float*)d_in[4];
    const float* W2  = (const float*)d_in[5];
    const float* b2  = (const float*)d_in[6];
    float* out       = (float*)d_out;

    const int N = in_sizes[2];       // 100000
    const int E = in_sizes[1] / 2;   // 1600000
    const int* src = edge;
    const int* dst = edge + E;

    const size_t fbuf = (size_t)N * FEAT * sizeof(float);
    const size_t abuf = (size_t)(N + 1) * FEAT * sizeof(unsigned short); // +zero row
    const int gE   = (E + 255) / 256;
    const int gN   = (N + 255) / 256;
    const int gN16 = (N + 15) / 16;
    const int gG   = (N + 63) / 64;
    const int gBH  = (E + BH_TILE - 1) / BH_TILE;
    const int nbScan = (N + SCAN_CHUNK - 1) / SCAN_CHUNK;
    const int KB = (N + BIN_R - 1) >> BIN_SHIFT;            // 196

    auto align256 = [](size_t v) { return (v + 255) & ~(size_t)255; };

    char* w = (char*)d_ws;
    size_t o = 0;
    float* dis  = (float*)(w + o); o = align256(o + (size_t)N * 4);
    float* cntf = (float*)(w + o); o = align256(o + (size_t)N * 4);
    int*   cntE = (int*)  (w + o); o = align256(o + (size_t)N * 4);   // gbc alias; adjacent to cntf
    int*   rp   = (int*)  (w + o); o = align256(o + (size_t)(N + 1) * 4);
    int*   ptot = (int*)  (w + o); o = align256(o + (size_t)1024 * 4); // bb aliases
    int*   poff = (int*)  (w + o); o = align256(o + (size_t)1024 * 4); // bcur aliases
    int*   col  = (int*)  (w + o); o = align256(o + (size_t)E * 4);
    size_t apsz = (size_t)E * 4 > abuf ? (size_t)E * 4 : abuf;
    char*  Ap   = w + o;           o = align256(o + apsz);            // pairs -> A2 (tier1) / A (tier2)
    const size_t need_base = o;
    unsigned short* Asep = (unsigned short*)(w + o); o = align256(o + abuf);
    unsigned short* wfrag = (unsigned short*)(w + o); o = align256(o + (size_t)FEAT * FEAT * 2);
    const size_t need_fused = o;

    int* gbc  = cntE;
    int* bb   = ptot;
    int* bcur = poff;
    unsigned* pairs = (unsigned*)Ap;
    unsigned short* A2t1 = (unsigned short*)Ap;  // tier1: A2 over dead pairs
    unsigned short* At2  = (unsigned short*)Ap;  // tier2: A over dead pairs
    unsigned short* Hb = (unsigned short*)out;   // tier2: bf16 H in out

    const bool binOK = (KB <= 256) && (N <= (1 << (32 - BIN_SHIFT - 1)));
    const long NF4 = (long)N * FEAT / 4;

    if (ws_size >= need_fused && binOK) {
        // zero cntf (N floats) + gbc (KB ints) in one shot (adjacent regions)
        size_t zspan = (size_t)((char*)gbc - (char*)cntf) + (size_t)KB * 4;
        hipMemsetAsync(cntf, 0, zspan, stream);
        k_bhist<<<gBH, 256, 0, stream>>>(dst, gbc, uidx, cntf, (uint4*)out, NF4, E, N, KB);
        k_bscan<<<1, 256, 0, stream>>>(gbc, bb, bcur, rp + N, KB, W2, wfrag);
        k_binA  <<<(E + BIN_TILE - 1) / BIN_TILE, 256, 0, stream>>>(src, dst, bcur, pairs, E, N, KB);
        k_binB2g<<<KB, 1024, 0, stream>>>(pairs, bb, rp, col, dis, x, W1, Asep, N);
        k_agg1f <<<gN16, 256, 0, stream>>>(Asep, rp, col, dis, b1, wfrag, A2t1, N);
        k_agg2s <<<gN16, 256, 0, stream>>>(A2t1, rp, col, dis, b2, uidx, cntf, out, N);
    } else if (ws_size >= need_base && binOK) {
        size_t zspan = (size_t)((char*)gbc - (char*)cntf) + (size_t)KB * 4;
        hipMemsetAsync(cntf, 0, zspan, stream);
        k_bhist<<<gBH, 256, 0, stream>>>(dst, gbc, uidx, cntf, (uint4*)nullptr, 0, E, N, KB);
        k_bscan<<<1, 256, 0, stream>>>(gbc, bb, bcur, rp + N, KB, (const float*)nullptr, (unsigned short*)nullptr);
        k_binA <<<(E + BIN_TILE - 1) / BIN_TILE, 256, 0, stream>>>(src, dst, bcur, pairs, E, N, KB);
        k_binB2<<<KB, 1024, 0, stream>>>(pairs, bb, rp, col, dis, N);

        k_gemm1<<<gG, 256, 0, stream>>>(x, W1, dis, At2, N);
        k_agg1 <<<gN16, 256, 0, stream>>>(At2, rp, col, dis, b1, Hb, N);
        k_gemm2<<<gG, 256, 0, stream>>>(Hb, W2, dis, At2, N);
        hipMemsetAsync(out, 0, fbuf, stream);
        k_agg2s<<<gN16, 256, 0, stream>>>(At2, rp, col, dis, b2, uidx, cntf, out, N);
    } else {
        hipMemsetAsync(cntE, 0, (size_t)N * 4, stream);
        k_hist <<<gE, 256, 0, stream>>>(dst, cntE, E, N);
        k_dis  <<<gN, 256, 0, stream>>>(cntE, dis, N);
        k_scan1<<<nbScan, SCAN_BS, 0, stream>>>(cntE, rp, ptot, N);
        k_scan2<<<1, 1024, 0, stream>>>(ptot, poff, rp + N, nbScan);
        k_scan3<<<nbScan, SCAN_BS, 0, stream>>>(rp, poff, N);
        hipMemsetAsync(cntE, 0, (size_t)N * 4, stream);
        k_fill <<<gE, 256, 0, stream>>>(src, dst, rp, cntE, col, E, N);
        hipMemsetAsync(cntf, 0, (size_t)N * 4, stream);
        k_ucnt <<<gN, 256, 0, stream>>>(uidx, cntf, N);
        k_gemm1<<<gG, 256, 0, stream>>>(x, W1, dis, At2, N);
        k_agg1 <<<gN16, 256, 0, stream>>>(At2, rp, col, dis, b1, Hb, N);
        k_gemm2<<<gG, 256, 0, stream>>>(Hb, W2, dis, At2, N);
        hipMemsetAsync(out, 0, fbuf, stream);
        k_agg2s<<<gN16, 256, 0, stream>>>(At2, rp, col, dis, b2, uidx, cntf, out, N);
    }
}

// Round 9
// 251.213 us; speedup vs baseline: 1.3051x; 1.0046x over previous
//
#include <hip/hip_runtime.h>
#include <hip/hip_bf16.h>

// GCN: h1 = relu(GCNConv(x, W1, b1)); out = scatter_mean(GCNConv(h1, W2, b2), user_idx)
// N=100000, E=1600000, dims 128 -> 64 -> 64. fp32 I/O, int32 indices.
//
// R20: agg kernels closed at the L2 random-request floor (~42us each, FETCH
// ~86MB = cross-XCD duplication of A; E distinct 128B-line requests at the
// TCC throughput limit; MLP-depth experiments R15/R16 proved insensitivity).
// R21: CSR build is issue-bound (~1TB/s, scalar 4B edge loads, double pairs
// pass): (1) bhist dst reads int4-vectorized; (2) binA src/dst int4;
// (3) binB2g single-pass col fill -- rank from the count-phase atomicAdd,
// pairs held in statically-indexed regs (k-unrolled, no scratch), second
// pairs pass + LDS-atomic round + barrier removed (nE<=9216 guard, two-pass
// fallback for oversized buckets).

#define FEAT 64
#define INDIM 128

#define SCAN_BS 256
#define SCAN_ELEMS 8
#define SCAN_CHUNK (SCAN_BS * SCAN_ELEMS)

#define BIN_SHIFT 9
#define BIN_R 512
#define BIN_TILE 2048
#define BH_TILE 2048

typedef __attribute__((ext_vector_type(8))) short short8;
typedef __attribute__((ext_vector_type(4))) float f32x4;

__device__ __forceinline__ unsigned short f2bf(float f) {
    unsigned u = __float_as_uint(f);
    unsigned r = u + 0x7FFFu + ((u >> 16) & 1u);
    return (unsigned short)(r >> 16);
}
__device__ __forceinline__ float bf2f(unsigned short v) {
    return __uint_as_float(((unsigned)v) << 16);
}

// ==================== bucket-level CSR build ====================

// histogram + ucnt + optional out-zeroing (NO fences -- see R18 post-mortem)
__global__ __launch_bounds__(256) void k_bhist(const int* __restrict__ dst,
                                               int* __restrict__ gbc,
                                               const int* __restrict__ uidx,
                                               float* __restrict__ cntf,
                                               uint4* __restrict__ outz, long nz4,
                                               int E, int N, int KB) {
    __shared__ int h[256];
    const int tid = threadIdx.x;
    h[tid] = 0;
    __syncthreads();
    const int base = blockIdx.x * BH_TILE;
    const bool al = ((((size_t)dst) & 15) == 0);
    #pragma unroll
    for (int t = 0; t < BH_TILE / 1024; ++t) {
        int e = base + t * 1024 + tid * 4;
        if (al && e + 3 < E) {
            int4 d4 = *reinterpret_cast<const int4*>(dst + e);
            if ((unsigned)d4.x < (unsigned)N) atomicAdd(&h[d4.x >> BIN_SHIFT], 1);
            if ((unsigned)d4.y < (unsigned)N) atomicAdd(&h[d4.y >> BIN_SHIFT], 1);
            if ((unsigned)d4.z < (unsigned)N) atomicAdd(&h[d4.z >> BIN_SHIFT], 1);
            if ((unsigned)d4.w < (unsigned)N) atomicAdd(&h[d4.w >> BIN_SHIFT], 1);
        } else {
            #pragma unroll
            for (int k = 0; k < 4; ++k) {
                int e2 = e + k;
                if (e2 < E) {
                    int d = dst[e2];
                    if ((unsigned)d < (unsigned)N) atomicAdd(&h[d >> BIN_SHIFT], 1);
                }
            }
        }
    }
    int i = blockIdx.x * 256 + tid;
    if (i < N) {
        int u = uidx[i];
        if ((unsigned)u < (unsigned)N) atomicAdd(&cntf[u], 1.0f);
    }
    if (outz) {
        uint4 z; z.x = 0; z.y = 0; z.z = 0; z.w = 0;
        const long stride = (long)gridDim.x * 256;
        for (long idx = (long)blockIdx.x * 256 + tid; idx < nz4; idx += stride)
            outz[idx] = z;
    }
    __syncthreads();
    if (tid < KB && h[tid]) atomicAdd(&gbc[tid], h[tid]);
}

// bucket scan + (optional) one-time W2 fragment-table precompute
__global__ __launch_bounds__(256) void k_bscan(const int* __restrict__ gbc,
                                               int* __restrict__ bb,
                                               int* __restrict__ bcur,
                                               int* __restrict__ rpN, int KB,
                                               const float* __restrict__ W2,
                                               unsigned short* __restrict__ wfrag) {
    __shared__ int lds[256];
    const int tid = threadIdx.x;
    if (wfrag) {
        for (int ii = tid; ii < FEAT * FEAT; ii += 256) {
            int k = ii >> 6, n = ii & 63;
            int ct = n >> 4, kc = k >> 5, r = k & 31;
            int owner = ((r >> 3) << 4) | (n & 15);
            wfrag[(((ct << 1) | kc) * 64 + owner) * 8 + (r & 7)] = f2bf(W2[ii]);
        }
    }
    int v = (tid < KB) ? gbc[tid] : 0;
    lds[tid] = v;
    __syncthreads();
    for (int d = 1; d < 256; d <<= 1) {
        int t = (tid >= d) ? lds[tid - d] : 0;
        __syncthreads();
        lds[tid] += t;
        __syncthreads();
    }
    int excl = lds[tid] - v;
    if (tid < KB) { bb[tid] = excl; bcur[tid] = excl; }
    if (tid == 255) { bb[KB] = lds[255]; *rpN = lds[255]; }
}

// tile-reorder edges by bucket; packed (src<<BIN_SHIFT)|local_dst
__global__ __launch_bounds__(256) void k_binA(const int* __restrict__ src,
                                              const int* __restrict__ dst,
                                              int* __restrict__ bcur,
                                              unsigned* __restrict__ pairs,
                                              int E, int N, int KB) {
    __shared__ unsigned lbuf[BIN_TILE];          // 8 KB
    __shared__ unsigned short bkt[BIN_TILE];     // 4 KB
    __shared__ int lcnt[256];
    __shared__ int loff[256];
    __shared__ int lbase[256];
    __shared__ int tot;
    const int tid = threadIdx.x;
    const int base = blockIdx.x * BIN_TILE;

    lcnt[tid] = 0;
    __syncthreads();

    int mys[8], myd[8], myb[8];
    const bool al = (((((size_t)src) | ((size_t)dst)) & 15) == 0);
    #pragma unroll
    for (int t = 0; t < 2; ++t) {
        int e = base + t * 1024 + tid * 4;
        int4 s4, d4;
        if (al && e + 3 < E) {
            s4 = *reinterpret_cast<const int4*>(src + e);
            d4 = *reinterpret_cast<const int4*>(dst + e);
        } else {
            s4.x = (e     < E) ? src[e]     : 0;  d4.x = (e     < E) ? dst[e]     : -1;
            s4.y = (e + 1 < E) ? src[e + 1] : 0;  d4.y = (e + 1 < E) ? dst[e + 1] : -1;
            s4.z = (e + 2 < E) ? src[e + 2] : 0;  d4.z = (e + 2 < E) ? dst[e + 2] : -1;
            s4.w = (e + 3 < E) ? src[e + 3] : 0;  d4.w = (e + 3 < E) ? dst[e + 3] : -1;
        }
        int ss[4] = {s4.x, s4.y, s4.z, s4.w};
        int dd[4] = {d4.x, d4.y, d4.z, d4.w};
        #pragma unroll
        for (int k = 0; k < 4; ++k) {
            int s = ss[k], d = dd[k];
            if ((unsigned)d >= (unsigned)N) d = -1;
            if ((unsigned)s >= (unsigned)N) s = 0;
            int j = t * 4 + k;
            mys[j] = s; myd[j] = d;
            myb[j] = (d >= 0) ? (d >> BIN_SHIFT) : -1;
            if (myb[j] >= 0) atomicAdd(&lcnt[myb[j]], 1);
        }
    }
    __syncthreads();

    int v = lcnt[tid];
    loff[tid] = v;
    __syncthreads();
    for (int d = 1; d < 256; d <<= 1) {
        int t2 = (tid >= d) ? loff[tid - d] : 0;
        __syncthreads();
        loff[tid] += t2;
        __syncthreads();
    }
    if (tid == 255) tot = loff[255];
    int excl = loff[tid] - v;
    __syncthreads();
    loff[tid] = excl;
    lcnt[tid] = excl;
    if (tid < KB && v > 0) lbase[tid] = atomicAdd(&bcur[tid], v);
    __syncthreads();

    #pragma unroll
    for (int j = 0; j < 8; ++j) {
        if (myb[j] >= 0) {
            int pos = atomicAdd(&lcnt[myb[j]], 1);
            lbuf[pos] = ((unsigned)mys[j] << BIN_SHIFT) | (unsigned)(myd[j] & (BIN_R - 1));
            bkt[pos] = (unsigned short)myb[j];
        }
    }
    __syncthreads();

    const int T = tot;
    for (int i = tid; i < T; i += 256) {
        int b = bkt[i];
        pairs[lbase[b] + (i - loff[b])] = lbuf[i];
    }
}

// FUSED binB2+gemm1: one WG (16 waves) per bucket of 512 nodes.
// Single-pass CSR fill: rank captured from the count-phase atomicAdd, pairs
// held in statically-indexed registers; col written after the scan (no second
// pairs pass). Two-pass fallback for buckets > 9216 edges.
__global__ __launch_bounds__(1024) void k_binB2g(const unsigned* __restrict__ pairs,
                                                 const int* __restrict__ bb,
                                                 int* __restrict__ rp,
                                                 int* __restrict__ col,
                                                 float* __restrict__ dis,
                                                 const float* __restrict__ x,
                                                 const float* __restrict__ W1,
                                                 unsigned short* __restrict__ A, int N) {
    __shared__ int cnt[BIN_R];
    __shared__ int cur[BIN_R];
    __shared__ int ssum[256];
    __shared__ short wf[4 * 4 * 64 * 8];   // W1 fragments, 16 KB
    const int tid = threadIdx.x;
    const int b = blockIdx.x;
    const int n0 = b << BIN_SHIFT;
    const int n1 = min(n0 + BIN_R, N);
    const int nn = n1 - n0;
    const int e0 = bb[b];
    const int e1 = bb[b + 1];
    const int nE = e1 - e0;
    const bool onepass = (nE <= 9 * 1024);

    for (int ii = tid; ii < INDIM * FEAT; ii += 1024) {
        int k = ii >> 6, n = ii & 63;
        int ct = n >> 4, kc = k >> 5, r = k & 31;
        int owner = ((r >> 3) << 4) | (n & 15);
        wf[(((ct << 2) | kc) * 64 + owner) * 8 + (r & 7)] = (short)f2bf(W1[ii]);
    }
    if (b == 0 && tid >= 512 && tid < 520) {      // zero row N of A
        uint4 z; z.x = 0; z.y = 0; z.z = 0; z.w = 0;
        *reinterpret_cast<uint4*>(A + (long)N * FEAT + (tid - 512) * 8) = z;
    }

    for (int i = tid; i < nn; i += 1024) cnt[i] = 0;
    __syncthreads();

    unsigned myp[9];
    int myr[9];
    if (onepass) {
        #pragma unroll
        for (int k = 0; k < 9; ++k) {
            int i = e0 + tid + k * 1024;
            if (i < e1) {
                unsigned pr = pairs[i];
                myp[k] = pr;
                myr[k] = atomicAdd(&cnt[pr & (BIN_R - 1)], 1);
            } else {
                myp[k] = 0xFFFFFFFFu;  // pairs < 2^26, sentinel safe
                myr[k] = 0;
            }
        }
    } else {
        for (int i = e0 + tid; i < e1; i += 1024)
            atomicAdd(&cnt[pairs[i] & (BIN_R - 1)], 1);
    }
    __syncthreads();

    const int i0 = 2 * tid;
    int c0 = 0, c1 = 0;
    if (tid < 256) {
        c0 = (i0     < nn) ? cnt[i0]     : 0;
        c1 = (i0 + 1 < nn) ? cnt[i0 + 1] : 0;
        ssum[tid] = c0 + c1;
    }
    __syncthreads();
    for (int d = 1; d < 256; d <<= 1) {
        int t = 0;
        if (tid < 256 && tid >= d) t = ssum[tid - d];
        __syncthreads();
        if (tid < 256) ssum[tid] += t;
        __syncthreads();
    }
    if (tid < 256) {
        int excl = ssum[tid] - (c0 + c1);
        if (i0 < nn) {
            cur[i0] = e0 + excl;
            rp[n0 + i0] = e0 + excl;
            dis[n0 + i0] = rsqrtf((float)c0 + 1.0f);
        }
        if (i0 + 1 < nn) {
            cur[i0 + 1] = e0 + excl + c0;
            rp[n0 + i0 + 1] = e0 + excl + c0;
            dis[n0 + i0 + 1] = rsqrtf((float)c1 + 1.0f);
        }
    }
    __syncthreads();

    if (onepass) {
        #pragma unroll
        for (int k = 0; k < 9; ++k) {
            unsigned pr = myp[k];
            if (pr != 0xFFFFFFFFu)
                col[cur[pr & (BIN_R - 1)] + myr[k]] = (int)(pr >> BIN_SHIFT);
        }
    } else {
        for (int i = e0 + tid; i < e1; i += 1024) {
            unsigned p = pairs[i];
            int pos = atomicAdd(&cur[p & (BIN_R - 1)], 1);
            col[pos] = (int)(p >> BIN_SHIFT);
        }
    }
    __syncthreads();

    // ---- gemm1 phase: 16 waves x 32 rows, MFMA 16x16x32 bf16 ----
    const int lane = tid & 63;
    const int w = tid >> 6;
    const int m = lane & 15, q = lane >> 4;
    #pragma unroll
    for (int t = 0; t < 2; ++t) {
        int lrow = w * 32 + t * 16 + m;
        int gr = n0 + lrow;
        int rl = gr < N ? gr : (N - 1);
        const float* xp = x + (long)rl * INDIM + q * 8;
        f32x4 acc[4] = {{0,0,0,0},{0,0,0,0},{0,0,0,0},{0,0,0,0}};
        #pragma unroll
        for (int kc = 0; kc < 4; ++kc) {
            float4 v0 = *reinterpret_cast<const float4*>(xp + kc * 32);
            float4 v1 = *reinterpret_cast<const float4*>(xp + kc * 32 + 4);
            short8 a;
            a[0]=(short)f2bf(v0.x); a[1]=(short)f2bf(v0.y); a[2]=(short)f2bf(v0.z); a[3]=(short)f2bf(v0.w);
            a[4]=(short)f2bf(v1.x); a[5]=(short)f2bf(v1.y); a[6]=(short)f2bf(v1.z); a[7]=(short)f2bf(v1.w);
            #pragma unroll
            for (int ct = 0; ct < 4; ++ct) {
                short8 bf = *reinterpret_cast<const short8*>(&wf[(((ct << 2) | kc) * 64 + lane) * 8]);
                acc[ct] = __builtin_amdgcn_mfma_f32_16x16x32_bf16(a, bf, acc[ct], 0, 0, 0);
            }
        }
        #pragma unroll
        for (int reg = 0; reg < 4; ++reg) {
            int ld = w * 32 + t * 16 + q * 4 + reg;
            if (ld < nn) {
                float sc = rsqrtf((float)cnt[ld] + 1.0f);
                int row = n0 + ld;
                #pragma unroll
                for (int ct = 0; ct < 4; ++ct)
                    A[(long)row * FEAT + ct * 16 + m] = f2bf(acc[ct][reg] * sc);
            }
        }
    }
}

// plain binB2 (fallback tiers)
__global__ __launch_bounds__(1024) void k_binB2(const unsigned* __restrict__ pairs,
                                                const int* __restrict__ bb,
                                                int* __restrict__ rp,
                                                int* __restrict__ col,
                                                float* __restrict__ dis, int N) {
    __shared__ int cnt[BIN_R];
    __shared__ int cur[BIN_R];
    __shared__ int ssum[256];
    const int tid = threadIdx.x;
    const int b = blockIdx.x;
    const int n0 = b << BIN_SHIFT;
    const int n1 = min(n0 + BIN_R, N);
    const int nn = n1 - n0;
    const int e0 = bb[b];
    const int e1 = bb[b + 1];

    for (int i = tid; i < nn; i += 1024) cnt[i] = 0;
    __syncthreads();
    for (int i = e0 + tid; i < e1; i += 1024) {
        atomicAdd(&cnt[pairs[i] & (BIN_R - 1)], 1);
    }
    __syncthreads();

    const int i0 = 2 * tid;
    int c0 = 0, c1 = 0;
    if (tid < 256) {
        c0 = (i0     < nn) ? cnt[i0]     : 0;
        c1 = (i0 + 1 < nn) ? cnt[i0 + 1] : 0;
        ssum[tid] = c0 + c1;
    }
    __syncthreads();
    for (int d = 1; d < 256; d <<= 1) {
        int t = 0;
        if (tid < 256 && tid >= d) t = ssum[tid - d];
        __syncthreads();
        if (tid < 256) ssum[tid] += t;
        __syncthreads();
    }
    if (tid < 256) {
        int excl = ssum[tid] - (c0 + c1);
        if (i0 < nn) {
            cur[i0] = e0 + excl;
            rp[n0 + i0] = e0 + excl;
            dis[n0 + i0] = rsqrtf((float)c0 + 1.0f);
        }
        if (i0 + 1 < nn) {
            cur[i0 + 1] = e0 + excl + c0;
            rp[n0 + i0 + 1] = e0 + excl + c0;
            dis[n0 + i0 + 1] = rsqrtf((float)c1 + 1.0f);
        }
    }
    __syncthreads();

    for (int i = e0 + tid; i < e1; i += 1024) {
        unsigned p = pairs[i];
        int pos = atomicAdd(&cur[p & (BIN_R - 1)], 1);
        col[pos] = (int)(p >> BIN_SHIFT);
    }
}

// ==================== fallback CSR build (proven path) ====================

__global__ __launch_bounds__(256) void k_hist(const int* __restrict__ dst,
                                              int* __restrict__ cntE, int E, int N) {
    int e = blockIdx.x * 256 + threadIdx.x;
    if (e < E) {
        int d = dst[e];
        if ((unsigned)d < (unsigned)N) atomicAdd(&cntE[d], 1);
    }
}
__global__ __launch_bounds__(256) void k_dis(const int* __restrict__ cntE,
                                             float* __restrict__ dis, int N) {
    int i = blockIdx.x * 256 + threadIdx.x;
    if (i < N) dis[i] = rsqrtf((float)cntE[i] + 1.0f);
}
__global__ __launch_bounds__(SCAN_BS) void k_scan1(const int* __restrict__ c,
                                                   int* __restrict__ rp,
                                                   int* __restrict__ ptot, int N) {
    __shared__ int lds[SCAN_BS];
    const int base = blockIdx.x * SCAN_CHUNK;
    const int tb = base + threadIdx.x * SCAN_ELEMS;
    int vals[SCAN_ELEMS];
    int s = 0;
    #pragma unroll
    for (int k = 0; k < SCAN_ELEMS; ++k) {
        int idx = tb + k;
        int v = (idx < N) ? c[idx] : 0;
        vals[k] = s;
        s += v;
    }
    lds[threadIdx.x] = s;
    __syncthreads();
    for (int d = 1; d < SCAN_BS; d <<= 1) {
        int v = (threadIdx.x >= d) ? lds[threadIdx.x - d] : 0;
        __syncthreads();
        lds[threadIdx.x] += v;
        __syncthreads();
    }
    int toff = (threadIdx.x == 0) ? 0 : lds[threadIdx.x - 1];
    #pragma unroll
    for (int k = 0; k < SCAN_ELEMS; ++k) {
        int idx = tb + k;
        if (idx < N) rp[idx] = toff + vals[k];
    }
    if (threadIdx.x == SCAN_BS - 1) ptot[blockIdx.x] = lds[SCAN_BS - 1];
}
__global__ __launch_bounds__(1024) void k_scan2(int* __restrict__ ptot,
                                                int* __restrict__ poff,
                                                int* __restrict__ rpN, int nb) {
    __shared__ int lds[1024];
    int tid = threadIdx.x;
    lds[tid] = (tid < nb) ? ptot[tid] : 0;
    __syncthreads();
    for (int d = 1; d < 1024; d <<= 1) {
        int v = (tid >= d) ? lds[tid - d] : 0;
        __syncthreads();
        lds[tid] += v;
        __syncthreads();
    }
    if (tid < nb) poff[tid] = (tid == 0) ? 0 : lds[tid - 1];
    if (tid == nb - 1) *rpN = lds[tid];
}
__global__ __launch_bounds__(SCAN_BS) void k_scan3(int* __restrict__ rp,
                                                   const int* __restrict__ poff, int N) {
    int off = poff[blockIdx.x];
    const int tb = blockIdx.x * SCAN_CHUNK + threadIdx.x * SCAN_ELEMS;
    #pragma unroll
    for (int k = 0; k < SCAN_ELEMS; ++k) {
        int idx = tb + k;
        if (idx < N) rp[idx] += off;
    }
}
__global__ __launch_bounds__(256) void k_fill(const int* __restrict__ src,
                                              const int* __restrict__ dst,
                                              const int* __restrict__ rp,
                                              int* __restrict__ tmp,
                                              int* __restrict__ col, int E, int N) {
    int e = blockIdx.x * 256 + threadIdx.x;
    if (e >= E) return;
    int s = src[e], d = dst[e];
    if ((unsigned)s >= (unsigned)N) s = 0;
    if ((unsigned)d >= (unsigned)N) return;
    int r = atomicAdd(&tmp[d], 1);
    col[rp[d] + r] = s;
}

__global__ __launch_bounds__(256) void k_ucnt(const int* __restrict__ uidx,
                                              float* __restrict__ cntf, int N) {
    int i = blockIdx.x * 256 + threadIdx.x;
    if (i < N) {
        int u = uidx[i];
        if ((unsigned)u < (unsigned)N) atomicAdd(&cntf[u], 1.0f);
    }
}

// ==================== MFMA GEMMs (fallback tiers) ====================

__global__ __launch_bounds__(256) void k_gemm1(const float* __restrict__ x,
                                               const float* __restrict__ W,
                                               const float* __restrict__ scale,
                                               unsigned short* __restrict__ out, int N) {
    __shared__ short wf[4 * 4 * 64 * 8];
    const int tid = threadIdx.x;
    if (blockIdx.x == 0 && tid < 8) {
        uint4 z; z.x = 0; z.y = 0; z.z = 0; z.w = 0;
        *reinterpret_cast<uint4*>(out + (long)N * FEAT + tid * 8) = z;
    }
    for (int i = tid; i < INDIM * FEAT; i += 256) {
        int k = i >> 6, n = i & 63;
        int ct = n >> 4, kc = k >> 5, r = k & 31;
        int owner = ((r >> 3) << 4) | (n & 15);
        wf[(((ct << 2) | kc) * 64 + owner) * 8 + (r & 7)] = (short)f2bf(W[i]);
    }
    __syncthreads();

    const int lane = tid & 63;
    const int m = lane & 15, q = lane >> 4;
    const int row0 = blockIdx.x * 64 + (tid >> 6) * 16;

    short8 bfr[4][4];
    #pragma unroll
    for (int ct = 0; ct < 4; ++ct)
        #pragma unroll
        for (int kc = 0; kc < 4; ++kc)
            bfr[ct][kc] = *reinterpret_cast<const short8*>(&wf[(((ct << 2) | kc) * 64 + lane) * 8]);

    int gr = row0 + m;
    int rl = gr < N ? gr : (N - 1);
    const float* xp = x + (long)rl * INDIM + q * 8;

    f32x4 acc[4] = {{0,0,0,0},{0,0,0,0},{0,0,0,0},{0,0,0,0}};
    #pragma unroll
    for (int kc = 0; kc < 4; ++kc) {
        float4 v0 = *reinterpret_cast<const float4*>(xp + kc * 32);
        float4 v1 = *reinterpret_cast<const float4*>(xp + kc * 32 + 4);
        short8 a;
        a[0]=(short)f2bf(v0.x); a[1]=(short)f2bf(v0.y); a[2]=(short)f2bf(v0.z); a[3]=(short)f2bf(v0.w);
        a[4]=(short)f2bf(v1.x); a[5]=(short)f2bf(v1.y); a[6]=(short)f2bf(v1.z); a[7]=(short)f2bf(v1.w);
        #pragma unroll
        for (int ct = 0; ct < 4; ++ct)
            acc[ct] = __builtin_amdgcn_mfma_f32_16x16x32_bf16(a, bfr[ct][kc], acc[ct], 0, 0, 0);
    }

    #pragma unroll
    for (int reg = 0; reg < 4; ++reg) {
        int row = row0 + q * 4 + reg;
        if (row < N) {
            float sc = scale[row];
            #pragma unroll
            for (int ct = 0; ct < 4; ++ct)
                out[(long)row * FEAT + ct * 16 + m] = f2bf(acc[ct][reg] * sc);
        }
    }
}

__global__ __launch_bounds__(256) void k_gemm2(const unsigned short* __restrict__ h,
                                               const float* __restrict__ W,
                                               const float* __restrict__ scale,
                                               unsigned short* __restrict__ out, int N) {
    __shared__ short wf[4 * 2 * 64 * 8];
    const int tid = threadIdx.x;
    if (blockIdx.x == 0 && tid < 8) {
        uint4 z; z.x = 0; z.y = 0; z.z = 0; z.w = 0;
        *reinterpret_cast<uint4*>(out + (long)N * FEAT + tid * 8) = z;
    }
    for (int i = tid; i < FEAT * FEAT; i += 256) {
        int k = i >> 6, n = i & 63;
        int ct = n >> 4, kc = k >> 5, r = k & 31;
        int owner = ((r >> 3) << 4) | (n & 15);
        wf[(((ct << 1) | kc) * 64 + owner) * 8 + (r & 7)] = (short)f2bf(W[i]);
    }
    __syncthreads();

    const int lane = tid & 63;
    const int m = lane & 15, q = lane >> 4;
    const int row0 = blockIdx.x * 64 + (tid >> 6) * 16;

    short8 bfr[4][2];
    #pragma unroll
    for (int ct = 0; ct < 4; ++ct)
        #pragma unroll
        for (int kc = 0; kc < 2; ++kc)
            bfr[ct][kc] = *reinterpret_cast<const short8*>(&wf[(((ct << 1) | kc) * 64 + lane) * 8]);

    int gr = row0 + m;
    int rl = gr < N ? gr : (N - 1);
    const unsigned short* hp = h + (long)rl * FEAT + q * 8;

    f32x4 acc[4] = {{0,0,0,0},{0,0,0,0},{0,0,0,0},{0,0,0,0}};
    #pragma unroll
    for (int kc = 0; kc < 2; ++kc) {
        short8 a = *reinterpret_cast<const short8*>(hp + kc * 32);
        #pragma unroll
        for (int ct = 0; ct < 4; ++ct)
            acc[ct] = __builtin_amdgcn_mfma_f32_16x16x32_bf16(a, bfr[ct][kc], acc[ct], 0, 0, 0);
    }

    #pragma unroll
    for (int reg = 0; reg < 4; ++reg) {
        int row = row0 + q * 4 + reg;
        if (row < N) {
            float sc = scale[row];
            #pragma unroll
            for (int ct = 0; ct < 4; ++ct)
                out[(long)row * FEAT + ct * 16 + m] = f2bf(acc[ct][reg] * sc);
        }
    }
}

// ==================== pull aggregation: 4 nodes/wave, 8 gathers in flight =====
// lane = 16*p + 8*s + ol (p = node 0..3, s = slot-parity 0..1, ol = octet).
// Each iteration covers 16 edges/node; 8 independent uint4 gathers in flight.
// Dummy slots read zero row N of A (L1-hot, adds 0). Reduce: one shfl_xor(8).

#define ACC8(r)                                                                  \
    a0 += bf2f((unsigned short)(r).x);                                           \
    a1 += bf2f((unsigned short)((r).x >> 16));                                   \
    a2 += bf2f((unsigned short)(r).y);                                           \
    a3 += bf2f((unsigned short)((r).y >> 16));                                   \
    a4 += bf2f((unsigned short)(r).z);                                           \
    a5 += bf2f((unsigned short)((r).z >> 16));                                   \
    a6 += bf2f((unsigned short)(r).w);                                           \
    a7 += bf2f((unsigned short)((r).w >> 16));

#define AGG_BODY(SELF_INIT)                                                      \
    const int lane = threadIdx.x & 63;                                           \
    const int wv = threadIdx.x >> 6;                                             \
    const int p  = lane >> 4;                                                    \
    const int s  = (lane >> 3) & 1;                                              \
    const int ol = lane & 7;                                                     \
    const int i  = blockIdx.x * 16 + wv * 4 + p;                                 \
    const bool valid = (i < N);                                                  \
    const int jb = valid ? rp[i] : 0;                                            \
    const int je = valid ? rp[i + 1] : 0;                                        \
    float a0=0.f,a1=0.f,a2=0.f,a3=0.f,a4=0.f,a5=0.f,a6=0.f,a7=0.f;               \
    if (valid && s == 0) { SELF_INIT }                                           \
    for (int j0 = jb; j0 < je; j0 += 16) {                                       \
        int j1 = j0 + s;                                                         \
        int c1 = (j1      < je) ? col[j1]      : N;                              \
        int c2 = (j1 + 2  < je) ? col[j1 + 2]  : N;                              \
        int c3 = (j1 + 4  < je) ? col[j1 + 4]  : N;                              \
        int c4 = (j1 + 6  < je) ? col[j1 + 6]  : N;                              \
        int c5 = (j1 + 8  < je) ? col[j1 + 8]  : N;                              \
        int c6 = (j1 + 10 < je) ? col[j1 + 10] : N;                              \
        int c7 = (j1 + 12 < je) ? col[j1 + 12] : N;                              \
        int c8 = (j1 + 14 < je) ? col[j1 + 14] : N;                              \
        uint4 r1 = *reinterpret_cast<const uint4*>(A + (long)c1 * FEAT + 8 * ol);\
        uint4 r2 = *reinterpret_cast<const uint4*>(A + (long)c2 * FEAT + 8 * ol);\
        uint4 r3 = *reinterpret_cast<const uint4*>(A + (long)c3 * FEAT + 8 * ol);\
        uint4 r4 = *reinterpret_cast<const uint4*>(A + (long)c4 * FEAT + 8 * ol);\
        uint4 r5 = *reinterpret_cast<const uint4*>(A + (long)c5 * FEAT + 8 * ol);\
        uint4 r6 = *reinterpret_cast<const uint4*>(A + (long)c6 * FEAT + 8 * ol);\
        uint4 r7 = *reinterpret_cast<const uint4*>(A + (long)c7 * FEAT + 8 * ol);\
        uint4 r8 = *reinterpret_cast<const uint4*>(A + (long)c8 * FEAT + 8 * ol);\
        ACC8(r1)                                                                 \
        ACC8(r2)                                                                 \
        ACC8(r3)                                                                 \
        ACC8(r4)                                                                 \
        ACC8(r5)                                                                 \
        ACC8(r6)                                                                 \
        ACC8(r7)                                                                 \
        ACC8(r8)                                                                 \
    }                                                                            \
    a0 += __shfl_xor(a0, 8);  a1 += __shfl_xor(a1, 8);                           \
    a2 += __shfl_xor(a2, 8);  a3 += __shfl_xor(a3, 8);                           \
    a4 += __shfl_xor(a4, 8);  a5 += __shfl_xor(a5, 8);                           \
    a6 += __shfl_xor(a6, 8);  a7 += __shfl_xor(a7, 8);

// mid-tier fallback: agg1 writes relu(di*sum + b) as PACKED BF16 to Hb
__global__ __launch_bounds__(256) void k_agg1(const unsigned short* __restrict__ A,
                                              const int* __restrict__ rp,
                                              const int* __restrict__ col,
                                              const float* __restrict__ dis,
                                              const float* __restrict__ bias,
                                              unsigned short* __restrict__ H, int N) {
    AGG_BODY(
        uint4 rv = *reinterpret_cast<const uint4*>(A + (long)i * FEAT + 8 * ol);
        a0 = bf2f((unsigned short)rv.x); a1 = bf2f((unsigned short)(rv.x >> 16));
        a2 = bf2f((unsigned short)rv.y); a3 = bf2f((unsigned short)(rv.y >> 16));
        a4 = bf2f((unsigned short)rv.z); a5 = bf2f((unsigned short)(rv.z >> 16));
        a6 = bf2f((unsigned short)rv.w); a7 = bf2f((unsigned short)(rv.w >> 16));
    )
    if (s == 0 && valid) {
        float di = dis[i];
        float4 b4a = *reinterpret_cast<const float4*>(bias + 8 * ol);
        float4 b4b = *reinterpret_cast<const float4*>(bias + 8 * ol + 4);
        uint4 o;
        o.x = (unsigned)f2bf(fmaxf(fmaf(di, a0, b4a.x), 0.f))
            | ((unsigned)f2bf(fmaxf(fmaf(di, a1, b4a.y), 0.f)) << 16);
        o.y = (unsigned)f2bf(fmaxf(fmaf(di, a2, b4a.z), 0.f))
            | ((unsigned)f2bf(fmaxf(fmaf(di, a3, b4a.w), 0.f)) << 16);
        o.z = (unsigned)f2bf(fmaxf(fmaf(di, a4, b4b.x), 0.f))
            | ((unsigned)f2bf(fmaxf(fmaf(di, a5, b4b.y), 0.f)) << 16);
        o.w = (unsigned)f2bf(fmaxf(fmaf(di, a6, b4b.z), 0.f))
            | ((unsigned)f2bf(fmaxf(fmaf(di, a7, b4b.w), 0.f)) << 16);
        *reinterpret_cast<uint4*>(H + (long)i * FEAT + 8 * ol) = o;
    }
}

// FUSED agg1+gemm2: block = 16 nodes = one 16x64 MFMA tile.
// W2 fragments come pre-converted from global (wfrag, L2-hot).
__global__ __launch_bounds__(256) void k_agg1f(const unsigned short* __restrict__ A,
                                               const int* __restrict__ rp,
                                               const int* __restrict__ col,
                                               const float* __restrict__ dis,
                                               const float* __restrict__ bias,
                                               const unsigned short* __restrict__ wfrag,
                                               unsigned short* __restrict__ A2, int N) {
    __shared__ unsigned short hh[16][72];      // h1 bf16, padded rows
    __shared__ float dl[16];
    const int tid = threadIdx.x;
    const int base16 = blockIdx.x * 16;
    if (tid < 16) {
        int node = base16 + tid;
        dl[tid] = (node < N) ? dis[node] : 0.f;
    }
    if (blockIdx.x == 0 && tid >= 32 && tid < 40) {
        uint4 z; z.x = 0; z.y = 0; z.z = 0; z.w = 0;
        *reinterpret_cast<uint4*>(A2 + (long)N * FEAT + (tid - 32) * 8) = z;
    }

    AGG_BODY(
        uint4 rv = *reinterpret_cast<const uint4*>(A + (long)i * FEAT + 8 * ol);
        a0 = bf2f((unsigned short)rv.x); a1 = bf2f((unsigned short)(rv.x >> 16));
        a2 = bf2f((unsigned short)rv.y); a3 = bf2f((unsigned short)(rv.y >> 16));
        a4 = bf2f((unsigned short)rv.z); a5 = bf2f((unsigned short)(rv.z >> 16));
        a6 = bf2f((unsigned short)rv.w); a7 = bf2f((unsigned short)(rv.w >> 16));
    )
    if (s == 0 && valid) {
        float di = dis[i];
        float4 b4a = *reinterpret_cast<const float4*>(bias + 8 * ol);
        float4 b4b = *reinterpret_cast<const float4*>(bias + 8 * ol + 4);
        uint4 o;
        o.x = (unsigned)f2bf(fmaxf(fmaf(di, a0, b4a.x), 0.f))
            | ((unsigned)f2bf(fmaxf(fmaf(di, a1, b4a.y), 0.f)) << 16);
        o.y = (unsigned)f2bf(fmaxf(fmaf(di, a2, b4a.z), 0.f))
            | ((unsigned)f2bf(fmaxf(fmaf(di, a3, b4a.w), 0.f)) << 16);
        o.z = (unsigned)f2bf(fmaxf(fmaf(di, a4, b4b.x), 0.f))
            | ((unsigned)f2bf(fmaxf(fmaf(di, a5, b4b.y), 0.f)) << 16);
        o.w = (unsigned)f2bf(fmaxf(fmaf(di, a6, b4b.z), 0.f))
            | ((unsigned)f2bf(fmaxf(fmaf(di, a7, b4b.w), 0.f)) << 16);
        *reinterpret_cast<uint4*>(&hh[wv * 4 + p][8 * ol]) = o;
    }
    __syncthreads();

    const int m = lane & 15, q = lane >> 4;
    short8 af0 = *reinterpret_cast<const short8*>(&hh[m][q * 8]);        // kc=0
    short8 af1 = *reinterpret_cast<const short8*>(&hh[m][32 + q * 8]);   // kc=1
    short8 bf0 = *reinterpret_cast<const short8*>(wfrag + (((wv << 1) | 0) * 64 + lane) * 8);
    short8 bf1 = *reinterpret_cast<const short8*>(wfrag + (((wv << 1) | 1) * 64 + lane) * 8);
    f32x4 acc = {0, 0, 0, 0};
    acc = __builtin_amdgcn_mfma_f32_16x16x32_bf16(af0, bf0, acc, 0, 0, 0);
    acc = __builtin_amdgcn_mfma_f32_16x16x32_bf16(af1, bf1, acc, 0, 0, 0);
    #pragma unroll
    for (int reg = 0; reg < 4; ++reg) {
        int node = q * 4 + reg;
        int row = base16 + node;
        if (row < N)
            A2[(long)row * FEAT + wv * 16 + m] = f2bf(acc[reg] * dl[node]);
    }
}

// agg2 + scatter: LDS-stage the 4 rows, then ONE full-wave 64-lane contiguous
// atomicAdd per node (256B/instr -> TCC merges to full-line RMW).
__global__ __launch_bounds__(256) void k_agg2s(const unsigned short* __restrict__ A,
                                               const int* __restrict__ rp,
                                               const int* __restrict__ col,
                                               const float* __restrict__ dis,
                                               const float* __restrict__ bias,
                                               const int* __restrict__ uidx,
                                               const float* __restrict__ cntf,
                                               float* __restrict__ S, int N) {
    __shared__ float sbuf[4][4][65];
    AGG_BODY(
        uint4 rv = *reinterpret_cast<const uint4*>(A + (long)i * FEAT + 8 * ol);
        a0 = bf2f((unsigned short)rv.x); a1 = bf2f((unsigned short)(rv.x >> 16));
        a2 = bf2f((unsigned short)rv.y); a3 = bf2f((unsigned short)(rv.y >> 16));
        a4 = bf2f((unsigned short)rv.z); a5 = bf2f((unsigned short)(rv.z >> 16));
        a6 = bf2f((unsigned short)rv.w); a7 = bf2f((unsigned short)(rv.w >> 16));
    )
    if (s == 0) {
        float* dl = &sbuf[wv][p][8 * ol];
        dl[0] = a0; dl[1] = a1; dl[2] = a2; dl[3] = a3;
        dl[4] = a4; dl[5] = a5; dl[6] = a6; dl[7] = a7;
    }
    __syncthreads();
    const int base4 = blockIdx.x * 16 + wv * 4;
    const float bl = bias[lane];
    #pragma unroll
    for (int pp = 0; pp < 4; ++pp) {
        int node = base4 + pp;
        if (node < N) {
            int u = uidx[node];
            if ((unsigned)u < (unsigned)N) {
                float c = cntf[u];
                float wgt = (c > 0.f) ? (1.0f / c) : 0.f;
                float di = dis[node];
                float v = sbuf[wv][pp][lane];
                atomicAdd(&S[(long)u * FEAT + lane], wgt * fmaf(di, v, bl));
            }
        }
    }
}

extern "C" void kernel_launch(void* const* d_in, const int* in_sizes, int n_in,
                              void* d_out, int out_size, void* d_ws, size_t ws_size,
                              hipStream_t stream) {
    const float* x   = (const float*)d_in[0];
    const int* edge  = (const int*)d_in[1];
    const int* uidx  = (const int*)d_in[2];
    const float* W1  = (const float*)d_in[3];
    const float* b1  = (const float*)d_in[4];
    const float* W2  = (const float*)d_in[5];
    const float* b2  = (const float*)d_in[6];
    float* out       = (float*)d_out;

    const int N = in_sizes[2];       // 100000
    const int E = in_sizes[1] / 2;   // 1600000
    const int* src = edge;
    const int* dst = edge + E;

    const size_t fbuf = (size_t)N * FEAT * sizeof(float);
    const size_t abuf = (size_t)(N + 1) * FEAT * sizeof(unsigned short); // +zero row
    const int gE   = (E + 255) / 256;
    const int gN   = (N + 255) / 256;
    const int gN16 = (N + 15) / 16;
    const int gG   = (N + 63) / 64;
    const int gBH  = (E + BH_TILE - 1) / BH_TILE;
    const int nbScan = (N + SCAN_CHUNK - 1) / SCAN_CHUNK;
    const int KB = (N + BIN_R - 1) >> BIN_SHIFT;            // 196

    auto align256 = [](size_t v) { return (v + 255) & ~(size_t)255; };

    char* w = (char*)d_ws;
    size_t o = 0;
    float* dis  = (float*)(w + o); o = align256(o + (size_t)N * 4);
    float* cntf = (float*)(w + o); o = align256(o + (size_t)N * 4);
    int*   cntE = (int*)  (w + o); o = align256(o + (size_t)N * 4);   // gbc alias; adjacent to cntf
    int*   rp   = (int*)  (w + o); o = align256(o + (size_t)(N + 1) * 4);
    int*   ptot = (int*)  (w + o); o = align256(o + (size_t)1024 * 4); // bb aliases
    int*   poff = (int*)  (w + o); o = align256(o + (size_t)1024 * 4); // bcur aliases
    int*   col  = (int*)  (w + o); o = align256(o + (size_t)E * 4);
    size_t apsz = (size_t)E * 4 > abuf ? (size_t)E * 4 : abuf;
    char*  Ap   = w + o;           o = align256(o + apsz);            // pairs -> A2 (tier1) / A (tier2)
    const size_t need_base = o;
    unsigned short* Asep = (unsigned short*)(w + o); o = align256(o + abuf);
    unsigned short* wfrag = (unsigned short*)(w + o); o = align256(o + (size_t)FEAT * FEAT * 2);
    const size_t need_fused = o;

    int* gbc  = cntE;
    int* bb   = ptot;
    int* bcur = poff;
    unsigned* pairs = (unsigned*)Ap;
    unsigned short* A2t1 = (unsigned short*)Ap;  // tier1: A2 over dead pairs
    unsigned short* At2  = (unsigned short*)Ap;  // tier2: A over dead pairs
    unsigned short* Hb = (unsigned short*)out;   // tier2: bf16 H in out

    const bool binOK = (KB <= 256) && (N <= (1 << (32 - BIN_SHIFT - 1)));
    const long NF4 = (long)N * FEAT / 4;

    if (ws_size >= need_fused && binOK) {
        // zero cntf (N floats) + gbc (KB ints) in one shot (adjacent regions)
        size_t zspan = (size_t)((char*)gbc - (char*)cntf) + (size_t)KB * 4;
        hipMemsetAsync(cntf, 0, zspan, stream);
        k_bhist<<<gBH, 256, 0, stream>>>(dst, gbc, uidx, cntf, (uint4*)out, NF4, E, N, KB);
        k_bscan<<<1, 256, 0, stream>>>(gbc, bb, bcur, rp + N, KB, W2, wfrag);
        k_binA  <<<(E + BIN_TILE - 1) / BIN_TILE, 256, 0, stream>>>(src, dst, bcur, pairs, E, N, KB);
        k_binB2g<<<KB, 1024, 0, stream>>>(pairs, bb, rp, col, dis, x, W1, Asep, N);
        k_agg1f <<<gN16, 256, 0, stream>>>(Asep, rp, col, dis, b1, wfrag, A2t1, N);
        k_agg2s <<<gN16, 256, 0, stream>>>(A2t1, rp, col, dis, b2, uidx, cntf, out, N);
    } else if (ws_size >= need_base && binOK) {
        size_t zspan = (size_t)((char*)gbc - (char*)cntf) + (size_t)KB * 4;
        hipMemsetAsync(cntf, 0, zspan, stream);
        k_bhist<<<gBH, 256, 0, stream>>>(dst, gbc, uidx, cntf, (uint4*)nullptr, 0, E, N, KB);
        k_bscan<<<1, 256, 0, stream>>>(gbc, bb, bcur, rp + N, KB, (const float*)nullptr, (unsigned short*)nullptr);
        k_binA <<<(E + BIN_TILE - 1) / BIN_TILE, 256, 0, stream>>>(src, dst, bcur, pairs, E, N, KB);
        k_binB2<<<KB, 1024, 0, stream>>>(pairs, bb, rp, col, dis, N);

        k_gemm1<<<gG, 256, 0, stream>>>(x, W1, dis, At2, N);
        k_agg1 <<<gN16, 256, 0, stream>>>(At2, rp, col, dis, b1, Hb, N);
        k_gemm2<<<gG, 256, 0, stream>>>(Hb, W2, dis, At2, N);
        hipMemsetAsync(out, 0, fbuf, stream);
        k_agg2s<<<gN16, 256, 0, stream>>>(At2, rp, col, dis, b2, uidx, cntf, out, N);
    } else {
        hipMemsetAsync(cntE, 0, (size_t)N * 4, stream);
        k_hist <<<gE, 256, 0, stream>>>(dst, cntE, E, N);
        k_dis  <<<gN, 256, 0, stream>>>(cntE, dis, N);
        k_scan1<<<nbScan, SCAN_BS, 0, stream>>>(cntE, rp, ptot, N);
        k_scan2<<<1, 1024, 0, stream>>>(ptot, poff, rp + N, nbScan);
        k_scan3<<<nbScan, SCAN_BS, 0, stream>>>(rp, poff, N);
        hipMemsetAsync(cntE, 0, (size_t)N * 4, stream);
        k_fill <<<gE, 256, 0, stream>>>(src, dst, rp, cntE, col, E, N);
        hipMemsetAsync(cntf, 0, (size_t)N * 4, stream);
        k_ucnt <<<gN, 256, 0, stream>>>(uidx, cntf, N);
        k_gemm1<<<gG, 256, 0, stream>>>(x, W1, dis, At2, N);
        k_agg1 <<<gN16, 256, 0, stream>>>(At2, rp, col, dis, b1, Hb, N);
        k_gemm2<<<gG, 256, 0, stream>>>(Hb, W2, dis, At2, N);
        hipMemsetAsync(out, 0, fbuf, stream);
        k_agg2s<<<gN16, 256, 0, stream>>>(At2, rp, col, dis, b2, uidx, cntf, out, N);
    }
}